// Round 9
// baseline (571.561 us; speedup 1.0000x reference)
//
#include <hip/hip_runtime.h>
#include <math.h>

#define PI2 6.283185307179586f

typedef __attribute__((ext_vector_type(8))) short bf16x8;
typedef __attribute__((ext_vector_type(4))) float f32x4;

__device__ __forceinline__ float gelu_f(float x) {
    return 0.5f * x * (1.0f + erff(x * 0.7071067811865476f));
}
__device__ __forceinline__ unsigned short f2bf(float f) {
    unsigned int u = __float_as_uint(f);
    u += 0x7FFFu + ((u >> 16) & 1u);
    return (unsigned short)(u >> 16);
}
__device__ __forceinline__ float bf2f(unsigned short h) {
    return __uint_as_float(((unsigned int)h) << 16);
}
__device__ __forceinline__ unsigned int pk(unsigned short a, unsigned short b) {
    return (unsigned int)a | ((unsigned int)b << 16);
}
// split fp32 weight into bf16 hi (dst[0]) + lo residual (dst[128])
__device__ __forceinline__ void wsplit(float w, unsigned short* dst) {
    unsigned short h = f2bf(w);
    dst[0] = h;
    dst[128] = f2bf(w - bf2f(h));
}

// ---- fused bases + fc0: FT[b][x][128] = [cos32; sin32; ch64] bf16,
//      wbb planes [b][k][x] (k<32 cos*w, 32..63 sin*w, 64 w), chbf planes [b][c][x].
//      NIN templated + full unroll so row[] stays in VGPRs (no scratch spill). ----
template<int NIN>
__global__ __launch_bounds__(256) void k_prep(const float* __restrict__ nodes, const float* __restrict__ modes,
                                              const float* __restrict__ latent, const float* __restrict__ nw,
                                              const float* __restrict__ inp, const float* __restrict__ fcw,
                                              const float* __restrict__ fcb,
                                              unsigned short* __restrict__ FT, unsigned short* __restrict__ wbb,
                                              unsigned short* __restrict__ chbf, int N) {
    int b = blockIdx.y;
    int x = blockIdx.x * 256 + threadIdx.x;
    float s0 = 0.5f + 1.5f / (1.0f + expf(-latent[0]));
    float s1 = 0.5f + 1.5f / (1.0f + expf(-latent[1]));
    float n0 = nodes[((size_t)b * N + x) * 2 + 0];
    float n1 = nodes[((size_t)b * N + x) * 2 + 1];
    float wx = nw[(size_t)b * N + x];
    unsigned short* wb = wbb + (size_t)b * 65 * N + x;
    unsigned int row[64];
    #pragma unroll
    for (int k = 0; k < 32; ++k) {
        float m0 = modes[k * 2 + 0] * s0;
        float m1 = modes[k * 2 + 1] * s1;
        float t = PI2 * (n0 * m0 + n1 * m1);
        float s, c;
        sincosf(t, &s, &c);
        unsigned short hc = f2bf(c), hs = f2bf(s);
        if (k & 1) { row[k >> 1] |= ((unsigned int)hc << 16); row[16 + (k >> 1)] |= ((unsigned int)hs << 16); }
        else       { row[k >> 1] = hc;                         row[16 + (k >> 1)] = hs; }
        wb[(size_t)k * N] = f2bf(c * wx);
        wb[(size_t)(32 + k) * N] = f2bf(s * wx);
    }
    wb[(size_t)64 * N] = f2bf(wx);
    // fc0 (fully unrolled -> static row[] indices)
    float xi[NIN];
    #pragma unroll
    for (int i = 0; i < NIN; ++i) xi[i] = inp[((size_t)b * N + x) * NIN + i];
    unsigned short* cb = chbf + (size_t)b * 64 * N + x;
    #pragma unroll
    for (int c = 0; c < 64; ++c) {
        float a = fcb[c];
        #pragma unroll
        for (int i = 0; i < NIN; ++i) a += fcw[c * NIN + i] * xi[i];
        unsigned short h = f2bf(a);
        cb[(size_t)c * N] = h;
        if (c & 1) row[32 + (c >> 1)] |= ((unsigned int)h << 16);
        else row[32 + (c >> 1)] = h;
    }
    unsigned int* fr = (unsigned int*)(FT + ((size_t)b * N + x) * 128);
    #pragma unroll
    for (int i = 0; i < 64; ++i) fr[i] = row[i];
}

// ---- fused analysis u+v (MFMA): partial[b][chunk][i][col] fp32 ----
__global__ __launch_bounds__(256) void k_analysis2(const unsigned short* __restrict__ chbf_u,
                                                   const unsigned short* __restrict__ wbb_u,
                                                   const unsigned short* __restrict__ chbf_v,
                                                   const unsigned short* __restrict__ wbb_v,
                                                   float* __restrict__ part_u, float* __restrict__ part_v,
                                                   int NU_, int NV_, int chu, int chv) {
    int b = blockIdx.y, bx = blockIdx.x, tid = threadIdx.x;
    const unsigned short *chb, *wb;
    float* pb;
    int N, xlen, chunk;
    if (bx < chu) {
        chunk = bx; N = NU_; xlen = NU_ / chu;
        chb = chbf_u + (size_t)b * 64 * N;
        wb = wbb_u + (size_t)b * 65 * N;
        pb = part_u + (size_t)(b * chu + chunk) * 64 * 66;
    } else {
        chunk = bx - chu; N = NV_; xlen = NV_ / chv;
        chb = chbf_v + (size_t)b * 64 * N;
        wb = wbb_v + (size_t)b * 65 * N;
        pb = part_v + (size_t)(b * chv + chunk) * 64 * 66;
    }
    int lane = tid & 63, wv = tid >> 6;
    int lm = lane & 15, lg = lane >> 4;
    int ro = wv * 16;
    int x0 = chunk * xlen;
    f32x4 acc[5] = {};
    for (int x = x0; x < x0 + xlen; x += 32) {
        bf16x8 a = *(const bf16x8*)(chb + (size_t)(ro + lm) * N + x + lg * 8);
        #pragma unroll
        for (int ct = 0; ct < 4; ++ct) {
            bf16x8 bf = *(const bf16x8*)(wb + (size_t)(ct * 16 + lm) * N + x + lg * 8);
            acc[ct] = __builtin_amdgcn_mfma_f32_16x16x32_bf16(a, bf, acc[ct], 0, 0, 0);
        }
        bf16x8 wf = *(const bf16x8*)(wb + (size_t)64 * N + x + lg * 8);
        acc[4] = __builtin_amdgcn_mfma_f32_16x16x32_bf16(a, wf, acc[4], 0, 0, 0);
    }
    #pragma unroll
    for (int ct = 0; ct < 4; ++ct)
        #pragma unroll
        for (int j = 0; j < 4; ++j)
            pb[(ro + lg * 4 + j) * 66 + ct * 16 + lm] = acc[ct][j];
    if (lm == 0) {
        #pragma unroll
        for (int j = 0; j < 4; ++j) pb[(ro + lg * 4 + j) * 66 + 64] = acc[4][j];
    }
}

// ---- fused reduce u+v -> mom[b][i][col] stride 66 ----
__global__ void k_reduce2(const float* __restrict__ part_u, const float* __restrict__ part_v,
                          float* __restrict__ momu, float* __restrict__ momv, int chu, int chv, int B_) {
    int by = blockIdx.y;
    const float* p;
    float* m;
    int nch, b;
    if (by < B_) { b = by; p = part_u; m = momu; nch = chu; }
    else { b = by - B_; p = part_v; m = momv; nch = chv; }
    int e = blockIdx.x * 256 + threadIdx.x;
    if (e >= 64 * 65) return;
    int row = e / 65, col = e % 65;
    const float* pp = p + ((size_t)(b * nch) * 64 + row) * 66 + col;
    float s = 0.f;
    #pragma unroll 4
    for (int c = 0; c < nch; ++c)
        s += pp[(size_t)c * 64 * 66];
    m[((size_t)b * 64 + row) * 66 + col] = s;
}

// ---- transpose weights (l,i,o,k)->(l,k,i,o) ----
__global__ __launch_bounds__(256) void k_tw(const float* __restrict__ e_c, const float* __restrict__ e_s,
                                            const float* __restrict__ u_c, const float* __restrict__ u_s,
                                            const float* __restrict__ v_c, const float* __restrict__ v_s,
                                            float* __restrict__ oT) {
    int li = blockIdx.x;
    int a = blockIdx.y;
    const float* in;
    switch (a) {
        case 0: in = e_c; break;
        case 1: in = e_s; break;
        case 2: in = u_c; break;
        case 3: in = u_s; break;
        case 4: in = v_c; break;
        default: in = v_s; break;
    }
    float* outp = oT + (size_t)a * 393216;
    int l = li >> 6, i = li & 63;
    __shared__ float t[32][65];
    int tid = threadIdx.x;
    const float* ib = in + (size_t)l * 131072 + (size_t)i * 2048;
    #pragma unroll
    for (int r = 0; r < 8; ++r) {
        int e = r * 256 + tid;
        t[e & 31][e >> 5] = ib[e];
    }
    __syncthreads();
    float* ob = outp + (size_t)l * 131072 + (size_t)i * 64;
    #pragma unroll
    for (int r = 0; r < 8; ++r) {
        int e = r * 256 + tid;
        ob[(size_t)(e >> 6) * 4096 + (e & 63)] = t[e >> 6][e & 63];
    }
}

// ---- buildW -> WBf[b][o][hi128|lo128] bf16 + bias[b][o] fp32 (split at write) ----
__global__ void k_buildW(const float* __restrict__ momu, const float* __restrict__ momv,
                         const float* __restrict__ ecT, const float* __restrict__ esT, const float* __restrict__ ew0,
                         const float* __restrict__ ucT, const float* __restrict__ usT, const float* __restrict__ uw0,
                         const float* __restrict__ vcT, const float* __restrict__ vsT, const float* __restrict__ vw0,
                         const float* __restrict__ wsuw, const float* __restrict__ wsub,
                         const float* __restrict__ wsvw, const float* __restrict__ wsvb,
                         unsigned short* __restrict__ WuBf, unsigned short* __restrict__ WvBf,
                         float* __restrict__ biasU, float* __restrict__ biasV, int do_v) {
    int b = blockIdx.y, j = blockIdx.x, o = threadIdx.x;
    const float* mu = momu + (size_t)b * 64 * 66;
    const float* mv = momv + (size_t)b * 64 * 66;
    unsigned short* Wub = WuBf + ((size_t)b * 64 + o) * 256;
    unsigned short* Wvb = WvBf + ((size_t)b * 64 + o) * 256;
    if (j < 32) {
        int k = j;
        const float* ec = ecT + (size_t)k * 4096;
        const float* es = esT + (size_t)k * 4096;
        const float* uc = ucT + (size_t)k * 4096;
        const float* us = usT + (size_t)k * 4096;
        const float* vc = vcT + (size_t)k * 4096;
        const float* vs = vsT + (size_t)k * 4096;
        float fcu = 0, fsu = 0, fcv = 0, fsv = 0;
        for (int i = 0; i < 64; ++i) {
            float Scv = mv[i * 66 + k], Ssv = mv[i * 66 + 32 + k];
            float Scu = mu[i * 66 + k], Ssu = mu[i * 66 + 32 + k];
            int wi = i * 64 + o;
            float e_c = ec[wi], e_s = es[wi];
            float u_c = uc[wi], u_s = us[wi];
            fcu += Scv * e_c + Ssv * e_s + Scu * u_c + Ssu * u_s;
            fsu += Scv * e_s - Ssv * e_c + Scu * u_s - Ssu * u_c;
            if (do_v) {
                float v_c = vc[wi], v_s = vs[wi];
                fcv += Scv * v_c + Ssv * v_s;
                fsv += Scv * v_s - Ssv * v_c;
            }
        }
        wsplit(2.f * fcu, Wub + k);
        wsplit(-2.f * fsu, Wub + 32 + k);
        if (do_v) {
            wsplit(2.f * fcv, Wvb + k);
            wsplit(-2.f * fsv, Wvb + 32 + k);
        }
    } else {
        for (int c = 0; c < 64; ++c) wsplit(wsuw[o * 64 + c], Wub + 64 + c);
        float f0u = 0;
        for (int i = 0; i < 64; ++i)
            f0u += mv[i * 66 + 64] * ew0[i * 64 + o] + mu[i * 66 + 64] * uw0[i * 64 + o];
        biasU[b * 64 + o] = f0u + wsub[o];
        if (do_v) {
            for (int c = 0; c < 64; ++c) wsplit(wsvw[o * 64 + c], Wvb + 64 + c);
            float f0v = 0;
            for (int i = 0; i < 64; ++i) f0v += mv[i * 66 + 64] * vw0[i * 64 + o];
            biasV[b * 64 + o] = f0v + wsvb[o];
        }
    }
}

// ---- fallback buildW (original weight layout) ----
__global__ void k_buildW_slow(const float* __restrict__ momu, const float* __restrict__ momv,
                              const float* __restrict__ ewc, const float* __restrict__ ews, const float* __restrict__ ew0,
                              const float* __restrict__ uwc, const float* __restrict__ uws, const float* __restrict__ uw0,
                              const float* __restrict__ vwc, const float* __restrict__ vws, const float* __restrict__ vw0,
                              const float* __restrict__ wsuw, const float* __restrict__ wsub,
                              const float* __restrict__ wsvw, const float* __restrict__ wsvb,
                              unsigned short* __restrict__ WuBf, unsigned short* __restrict__ WvBf,
                              float* __restrict__ biasU, float* __restrict__ biasV, int do_v) {
    int b = blockIdx.y, j = blockIdx.x, o = threadIdx.x;
    const float* mu = momu + (size_t)b * 64 * 66;
    const float* mv = momv + (size_t)b * 64 * 66;
    unsigned short* Wub = WuBf + ((size_t)b * 64 + o) * 256;
    unsigned short* Wvb = WvBf + ((size_t)b * 64 + o) * 256;
    if (j < 32) {
        int k = j;
        float fcu = 0, fsu = 0, fcv = 0, fsv = 0;
        for (int i = 0; i < 64; ++i) {
            float Scv = mv[i * 66 + k], Ssv = mv[i * 66 + 32 + k];
            float Scu = mu[i * 66 + k], Ssu = mu[i * 66 + 32 + k];
            int wi = (i * 64 + o) * 32 + k;
            float ec = ewc[wi], es = ews[wi];
            float uc = uwc[wi], us = uws[wi];
            fcu += Scv * ec + Ssv * es + Scu * uc + Ssu * us;
            fsu += Scv * es - Ssv * ec + Scu * us - Ssu * uc;
            if (do_v) {
                float vc = vwc[wi], vs = vws[wi];
                fcv += Scv * vc + Ssv * vs;
                fsv += Scv * vs - Ssv * vc;
            }
        }
        wsplit(2.f * fcu, Wub + k);
        wsplit(-2.f * fsu, Wub + 32 + k);
        if (do_v) {
            wsplit(2.f * fcv, Wvb + k);
            wsplit(-2.f * fsv, Wvb + 32 + k);
        }
    } else {
        for (int c = 0; c < 64; ++c) wsplit(wsuw[o * 64 + c], Wub + 64 + c);
        float f0u = 0;
        for (int i = 0; i < 64; ++i)
            f0u += mv[i * 66 + 64] * ew0[i * 64 + o] + mu[i * 66 + 64] * uw0[i * 64 + o];
        biasU[b * 64 + o] = f0u + wsub[o];
        if (do_v) {
            for (int c = 0; c < 64; ++c) wsplit(wsvw[o * 64 + c], Wvb + 64 + c);
            float f0v = 0;
            for (int i = 0; i < 64; ++i) f0v += mv[i * 66 + 64] * vw0[i * 64 + o];
            biasV[b * 64 + o] = f0v + wsvb[o];
        }
    }
}

// ---- fused synthesis u+v (MFMA): out = act(Wbf(hi+lo) . FT[x][128] + bias)
// LDS-staged output tile -> all HBM writes are 64B-contiguous per lane ----
__global__ __launch_bounds__(256) void k_synth2(const unsigned short* __restrict__ WuBf,
                                                const unsigned short* __restrict__ WvBf,
                                                const float* __restrict__ biasU, const float* __restrict__ biasV,
                                                unsigned short* FTu, unsigned short* FTv,
                                                unsigned short* __restrict__ cbu, unsigned short* __restrict__ cbv,
                                                int NU_, int NV_, int nbu, int act_u, int wch_u) {
    int bx = blockIdx.x, b = blockIdx.y, tid = threadIdx.x;
    const unsigned short* Wb;
    const float* bi;
    unsigned short *FT, *cbp;
    int N, act, wch, blk;
    if (bx < nbu) { Wb = WuBf; bi = biasU; FT = FTu; cbp = cbu; N = NU_; act = act_u; wch = wch_u; blk = bx; }
    else { Wb = WvBf; bi = biasV; FT = FTv; cbp = cbv; N = NV_; act = 1; wch = 1; blk = bx - nbu; }
    int lane = tid & 63, wv = tid >> 6;
    int lm = lane & 15, lg = lane >> 4;
    const unsigned short* Wrow = Wb + ((size_t)b * 64 + 16 * wv + lm) * 256;
    bf16x8 ahi[4], alo[4];
    #pragma unroll
    for (int kt = 0; kt < 4; ++kt) {
        ahi[kt] = *(const bf16x8*)(Wrow + kt * 32 + lg * 8);
        alo[kt] = *(const bf16x8*)(Wrow + 128 + kt * 32 + lg * 8);
    }
    float bias[4];
    #pragma unroll
    for (int j = 0; j < 4; ++j) bias[j] = bi[b * 64 + 16 * wv + lg * 4 + j];
    f32x4 acc[8] = {};
    unsigned short* ftb = FT + (size_t)b * N * 128;
    int x0 = blk * 128;
    #pragma unroll
    for (int xt = 0; xt < 8; ++xt) {
        int x = x0 + xt * 16 + lm;
        const unsigned short* fp = ftb + (size_t)x * 128 + lg * 8;
        #pragma unroll
        for (int kt = 0; kt < 4; ++kt) {
            bf16x8 bf = *(const bf16x8*)(fp + kt * 32);
            acc[xt] = __builtin_amdgcn_mfma_f32_16x16x32_bf16(ahi[kt], bf, acc[xt], 0, 0, 0);
            acc[xt] = __builtin_amdgcn_mfma_f32_16x16x32_bf16(alo[kt], bf, acc[xt], 0, 0, 0);
        }
    }
    // stage activated tile [128 x][64 c] in LDS (stride 68 shorts to spread banks)
    __shared__ unsigned short st[128][68];
    int r0 = 16 * wv + lg * 4;
    #pragma unroll
    for (int xt = 0; xt < 8; ++xt) {
        int xl = xt * 16 + lm;
        float v[4];
        #pragma unroll
        for (int j = 0; j < 4; ++j) {
            v[j] = acc[xt][j] + bias[j];
            if (act) v[j] = gelu_f(v[j]);
        }
        *(unsigned int*)&st[xl][r0] = pk(f2bf(v[0]), f2bf(v[1]));
        *(unsigned int*)&st[xl][r0 + 2] = pk(f2bf(v[2]), f2bf(v[3]));
    }
    // barrier: covers LDS visibility AND all-FT-reads-before-in-place-write hazard
    __syncthreads();
    // FT ch-cols: thread -> (x-row, half); 64B contiguous global write per thread
    {
        int xl = tid >> 1, half = tid & 1;
        unsigned int r[16];
        #pragma unroll
        for (int i = 0; i < 16; ++i) r[i] = *(const unsigned int*)&st[xl][half * 32 + i * 2];
        unsigned int* dst = (unsigned int*)(ftb + (size_t)(x0 + xl) * 128 + 64 + half * 32);
        #pragma unroll
        for (int i = 0; i < 4; ++i)
            ((uint4*)dst)[i] = make_uint4(r[4 * i], r[4 * i + 1], r[4 * i + 2], r[4 * i + 3]);
    }
    // chbf planes: thread -> (channel, x-chunk); 64B contiguous global write per thread
    if (wch) {
        int c = tid & 63, xc = tid >> 6;
        unsigned int r[16];
        #pragma unroll
        for (int i = 0; i < 16; ++i)
            r[i] = pk(st[xc * 32 + 2 * i][c], st[xc * 32 + 2 * i + 1][c]);
        unsigned int* dst = (unsigned int*)(cbp + (size_t)c * N + x0 + xc * 32);
        #pragma unroll
        for (int i = 0; i < 4; ++i)
            ((uint4*)dst)[i] = make_uint4(r[4 * i], r[4 * i + 1], r[4 * i + 2], r[4 * i + 3]);
    }
}

// ---- fc1(gelu)+fc2 fused, MFMA from FT ch-cols ----
__global__ __launch_bounds__(256) void k_fc12(const unsigned short* __restrict__ FT, const float* __restrict__ w1,
                                              const float* __restrict__ b1, const float* __restrict__ w2,
                                              const float* __restrict__ b2, float* __restrict__ out, int N) {
    int b = blockIdx.y, blk = blockIdx.x, tid = threadIdx.x;
    int lane = tid & 63, wv = tid >> 6;
    int lm = lane & 15, lg = lane >> 4;
    int f0 = wv * 32;
    bf16x8 ahi[2][2], alo[2][2];
    #pragma unroll
    for (int ft = 0; ft < 2; ++ft)
        #pragma unroll
        for (int kt = 0; kt < 2; ++kt) {
            const float* wp = w1 + (size_t)(f0 + ft * 16 + lm) * 64 + kt * 32 + lg * 8;
            float tmp[8];
            *(float4*)&tmp[0] = *(const float4*)wp;
            *(float4*)&tmp[4] = *(const float4*)(wp + 4);
            #pragma unroll
            for (int i = 0; i < 8; ++i) {
                unsigned short h = f2bf(tmp[i]);
                ahi[ft][kt][i] = (short)h;
                alo[ft][kt][i] = (short)f2bf(tmp[i] - bf2f(h));
            }
        }
    float b1v[2][4], w2v[2][4];
    #pragma unroll
    for (int ft = 0; ft < 2; ++ft)
        #pragma unroll
        for (int j = 0; j < 4; ++j) {
            int f = f0 + ft * 16 + lg * 4 + j;
            b1v[ft][j] = b1[f];
            w2v[ft][j] = w2[f];
        }
    f32x4 acc[8][2] = {};
    const unsigned short* ftb = FT + (size_t)b * N * 128;
    int x0 = blk * 128;
    #pragma unroll
    for (int xt = 0; xt < 8; ++xt) {
        const unsigned short* fp = ftb + (size_t)(x0 + xt * 16 + lm) * 128 + 64 + lg * 8;
        bf16x8 bf0 = *(const bf16x8*)fp;
        bf16x8 bf1 = *(const bf16x8*)(fp + 32);
        #pragma unroll
        for (int ft = 0; ft < 2; ++ft) {
            acc[xt][ft] = __builtin_amdgcn_mfma_f32_16x16x32_bf16(ahi[ft][0], bf0, acc[xt][ft], 0, 0, 0);
            acc[xt][ft] = __builtin_amdgcn_mfma_f32_16x16x32_bf16(alo[ft][0], bf0, acc[xt][ft], 0, 0, 0);
            acc[xt][ft] = __builtin_amdgcn_mfma_f32_16x16x32_bf16(ahi[ft][1], bf1, acc[xt][ft], 0, 0, 0);
            acc[xt][ft] = __builtin_amdgcn_mfma_f32_16x16x32_bf16(alo[ft][1], bf1, acc[xt][ft], 0, 0, 0);
        }
    }
    __shared__ float red[4][8][16];
    #pragma unroll
    for (int xt = 0; xt < 8; ++xt) {
        float s = 0.f;
        #pragma unroll
        for (int ft = 0; ft < 2; ++ft)
            #pragma unroll
            for (int j = 0; j < 4; ++j) {
                float v = acc[xt][ft][j] + b1v[ft][j];
                s += w2v[ft][j] * gelu_f(v);
            }
        s += __shfl_xor(s, 16, 64);
        s += __shfl_xor(s, 32, 64);
        if (lg == 0) red[wv][xt][lm] = s;
    }
    __syncthreads();
    if (tid < 128) {
        int xt = tid >> 4, lmm = tid & 15;
        float s = b2[0] + red[0][xt][lmm] + red[1][xt][lmm] + red[2][xt][lmm] + red[3][xt][lmm];
        out[(size_t)b * N + x0 + tid] = s;
    }
}

extern "C" void kernel_launch(void* const* d_in, const int* in_sizes, int n_in,
                              void* d_out, int out_size, void* d_ws, size_t ws_size,
                              hipStream_t stream) {
    const float* u_in = (const float*)d_in[0];
    const float* v_in = (const float*)d_in[1];
    const float* nodes_u = (const float*)d_in[3];
    const float* nodes_v = (const float*)d_in[4];
    const float* nwu = (const float*)d_in[5];
    const float* nwv = (const float*)d_in[6];
    const float* modes = (const float*)d_in[7];
    const float* latent = (const float*)d_in[8];
    const float* fc0uw = (const float*)d_in[9];
    const float* fc0ub = (const float*)d_in[10];
    const float* fc0vw = (const float*)d_in[11];
    const float* fc0vb = (const float*)d_in[12];
    const float* ewc = (const float*)d_in[13];
    const float* ews = (const float*)d_in[14];
    const float* ew0 = (const float*)d_in[15];
    const float* uwc = (const float*)d_in[16];
    const float* uws = (const float*)d_in[17];
    const float* uw0 = (const float*)d_in[18];
    const float* vwc = (const float*)d_in[19];
    const float* vws = (const float*)d_in[20];
    const float* vw0 = (const float*)d_in[21];
    const float* wsuw = (const float*)d_in[22];
    const float* wsub = (const float*)d_in[23];
    const float* wsvw = (const float*)d_in[24];
    const float* wsvb = (const float*)d_in[25];
    const float* fc1w = (const float*)d_in[26];
    const float* fc1b = (const float*)d_in[27];
    const float* fc2w = (const float*)d_in[28];
    const float* fc2b = (const float*)d_in[29];
    float* out = (float*)d_out;

    const int B = 4, NU = 65536, NV = 16384;
    const int CH_U = 256, CH_V = 128;

    unsigned short* FT_u = (unsigned short*)d_ws;
    unsigned short* FT_v = FT_u + (size_t)B * NU * 128;
    unsigned short* wbb_u = FT_v + (size_t)B * NV * 128;
    unsigned short* wbb_v = wbb_u + (size_t)B * 65 * NU;
    unsigned short* chbf_u = wbb_v + (size_t)B * 65 * NV;
    unsigned short* chbf_v = chbf_u + (size_t)B * 64 * NU;
    float* part_u = (float*)(chbf_v + (size_t)B * 64 * NV);
    float* part_v = part_u + (size_t)B * CH_U * 64 * 66;
    float* momu = part_v + (size_t)B * CH_V * 64 * 66;
    float* momv = momu + B * 64 * 66;
    unsigned short* WuBf = (unsigned short*)(momv + B * 64 * 66);
    unsigned short* WvBf = WuBf + (size_t)B * 64 * 256;
    float* biasU = (float*)(WvBf + (size_t)B * 64 * 256);
    float* biasV = biasU + B * 64;
    float* wT = biasV + B * 64;
    size_t need_T = (size_t)((char*)(wT + 6 * 393216) - (char*)d_ws);
    int use_T = (ws_size >= need_T) ? 1 : 0;

    k_prep<2><<<dim3(NU / 256, B), 256, 0, stream>>>(nodes_u, modes, latent, nwu, u_in, fc0uw, fc0ub,
                                                     FT_u, wbb_u, chbf_u, NU);
    k_prep<3><<<dim3(NV / 256, B), 256, 0, stream>>>(nodes_v, modes, latent, nwv, v_in, fc0vw, fc0vb,
                                                     FT_v, wbb_v, chbf_v, NV);
    if (use_T)
        k_tw<<<dim3(192, 6), 256, 0, stream>>>(ewc, ews, uwc, uws, vwc, vws, wT);

    for (int l = 0; l < 3; ++l) {
        int do_v = (l < 2) ? 1 : 0;
        k_analysis2<<<dim3(CH_U + CH_V, B), 256, 0, stream>>>(chbf_u, wbb_u, chbf_v, wbb_v,
                                                              part_u, part_v, NU, NV, CH_U, CH_V);
        k_reduce2<<<dim3(17, 2 * B), 256, 0, stream>>>(part_u, part_v, momu, momv, CH_U, CH_V, B);
        if (use_T) {
            k_buildW<<<dim3(33, B), 64, 0, stream>>>(momu, momv,
                wT + 0 * 393216 + l * 131072, wT + 1 * 393216 + l * 131072, ew0 + (size_t)l * 64 * 64,
                wT + 2 * 393216 + l * 131072, wT + 3 * 393216 + l * 131072, uw0 + (size_t)l * 64 * 64,
                wT + 4 * 393216 + l * 131072, wT + 5 * 393216 + l * 131072, vw0 + (size_t)l * 64 * 64,
                wsuw + l * 64 * 64, wsub + l * 64, wsvw + l * 64 * 64, wsvb + l * 64,
                WuBf, WvBf, biasU, biasV, do_v);
        } else {
            k_buildW_slow<<<dim3(33, B), 64, 0, stream>>>(momu, momv,
                ewc + (size_t)l * 64 * 64 * 32, ews + (size_t)l * 64 * 64 * 32, ew0 + (size_t)l * 64 * 64,
                uwc + (size_t)l * 64 * 64 * 32, uws + (size_t)l * 64 * 64 * 32, uw0 + (size_t)l * 64 * 64,
                vwc + (size_t)l * 64 * 64 * 32, vws + (size_t)l * 64 * 64 * 32, vw0 + (size_t)l * 64 * 64,
                wsuw + l * 64 * 64, wsub + l * 64, wsvw + l * 64 * 64, wsvb + l * 64,
                WuBf, WvBf, biasU, biasV, do_v);
        }
        int nbu = NU / 128;
        int nbx = nbu + (do_v ? NV / 128 : 0);
        k_synth2<<<dim3(nbx, B), 256, 0, stream>>>(WuBf, WvBf, biasU, biasV, FT_u, FT_v, chbf_u, chbf_v,
                                                   NU, NV, nbu, do_v, do_v);
    }
    k_fc12<<<dim3(NU / 128, B), 256, 0, stream>>>(FT_u, fc1w, fc1b, fc2w, fc2b, out, NU);
}

// Round 10
// 525.625 us; speedup vs baseline: 1.0874x; 1.0874x over previous
//
#include <hip/hip_runtime.h>
#include <math.h>

#define PI2 6.283185307179586f

typedef __attribute__((ext_vector_type(8))) short bf16x8;
typedef __attribute__((ext_vector_type(4))) float f32x4;

__device__ __forceinline__ float gelu_f(float x) {
    return 0.5f * x * (1.0f + erff(x * 0.7071067811865476f));
}
__device__ __forceinline__ unsigned short f2bf(float f) {
    unsigned int u = __float_as_uint(f);
    u += 0x7FFFu + ((u >> 16) & 1u);
    return (unsigned short)(u >> 16);
}
__device__ __forceinline__ float bf2f(unsigned short h) {
    return __uint_as_float(((unsigned int)h) << 16);
}
__device__ __forceinline__ unsigned int pk(unsigned short a, unsigned short b) {
    return (unsigned int)a | ((unsigned int)b << 16);
}
// split fp32 weight into bf16 hi (dst[0]) + lo residual (dst[128])
__device__ __forceinline__ void wsplit(float w, unsigned short* dst) {
    unsigned short h = f2bf(w);
    dst[0] = h;
    dst[128] = f2bf(w - bf2f(h));
}

// ---- fused bases + fc0: FT[b][x][128] = [cos32; sin32; ch64] bf16,
//      wbb planes [b][k][x] (k<32 cos*w, 32..63 sin*w, 64 w), chbf planes [b][c][x]. ----
template<int NIN>
__global__ __launch_bounds__(256) void k_prep(const float* __restrict__ nodes, const float* __restrict__ modes,
                                              const float* __restrict__ latent, const float* __restrict__ nw,
                                              const float* __restrict__ inp, const float* __restrict__ fcw,
                                              const float* __restrict__ fcb,
                                              unsigned short* __restrict__ FT, unsigned short* __restrict__ wbb,
                                              unsigned short* __restrict__ chbf, int N) {
    int b = blockIdx.y;
    int x = blockIdx.x * 256 + threadIdx.x;
    float s0 = 0.5f + 1.5f / (1.0f + expf(-latent[0]));
    float s1 = 0.5f + 1.5f / (1.0f + expf(-latent[1]));
    float n0 = nodes[((size_t)b * N + x) * 2 + 0];
    float n1 = nodes[((size_t)b * N + x) * 2 + 1];
    float wx = nw[(size_t)b * N + x];
    unsigned short* wb = wbb + (size_t)b * 65 * N + x;
    unsigned int row[64];
    #pragma unroll
    for (int k = 0; k < 32; ++k) {
        float m0 = modes[k * 2 + 0] * s0;
        float m1 = modes[k * 2 + 1] * s1;
        float t = PI2 * (n0 * m0 + n1 * m1);
        float s, c;
        sincosf(t, &s, &c);
        unsigned short hc = f2bf(c), hs = f2bf(s);
        if (k & 1) { row[k >> 1] |= ((unsigned int)hc << 16); row[16 + (k >> 1)] |= ((unsigned int)hs << 16); }
        else       { row[k >> 1] = hc;                         row[16 + (k >> 1)] = hs; }
        wb[(size_t)k * N] = f2bf(c * wx);
        wb[(size_t)(32 + k) * N] = f2bf(s * wx);
    }
    wb[(size_t)64 * N] = f2bf(wx);
    float xi[NIN];
    #pragma unroll
    for (int i = 0; i < NIN; ++i) xi[i] = inp[((size_t)b * N + x) * NIN + i];
    unsigned short* cb = chbf + (size_t)b * 64 * N + x;
    #pragma unroll
    for (int c = 0; c < 64; ++c) {
        float a = fcb[c];
        #pragma unroll
        for (int i = 0; i < NIN; ++i) a += fcw[c * NIN + i] * xi[i];
        unsigned short h = f2bf(a);
        cb[(size_t)c * N] = h;
        if (c & 1) row[32 + (c >> 1)] |= ((unsigned int)h << 16);
        else row[32 + (c >> 1)] = h;
    }
    unsigned int* fr = (unsigned int*)(FT + ((size_t)b * N + x) * 128);
    #pragma unroll
    for (int i = 0; i < 64; ++i) fr[i] = row[i];
}

// ---- analysis u+v (MFMA) from chbf planes: only needed for layer 0 ----
__global__ __launch_bounds__(256) void k_analysis2(const unsigned short* __restrict__ chbf_u,
                                                   const unsigned short* __restrict__ wbb_u,
                                                   const unsigned short* __restrict__ chbf_v,
                                                   const unsigned short* __restrict__ wbb_v,
                                                   float* __restrict__ part_u, float* __restrict__ part_v,
                                                   int NU_, int NV_, int chu, int chv) {
    int b = blockIdx.y, bx = blockIdx.x, tid = threadIdx.x;
    const unsigned short *chb, *wb;
    float* pb;
    int N, xlen, chunk;
    if (bx < chu) {
        chunk = bx; N = NU_; xlen = NU_ / chu;
        chb = chbf_u + (size_t)b * 64 * N;
        wb = wbb_u + (size_t)b * 65 * N;
        pb = part_u + (size_t)(b * chu + chunk) * 64 * 66;
    } else {
        chunk = bx - chu; N = NV_; xlen = NV_ / chv;
        chb = chbf_v + (size_t)b * 64 * N;
        wb = wbb_v + (size_t)b * 65 * N;
        pb = part_v + (size_t)(b * chv + chunk) * 64 * 66;
    }
    int lane = tid & 63, wv = tid >> 6;
    int lm = lane & 15, lg = lane >> 4;
    int ro = wv * 16;
    int x0 = chunk * xlen;
    f32x4 acc[5] = {};
    for (int x = x0; x < x0 + xlen; x += 32) {
        bf16x8 a = *(const bf16x8*)(chb + (size_t)(ro + lm) * N + x + lg * 8);
        #pragma unroll
        for (int ct = 0; ct < 4; ++ct) {
            bf16x8 bf = *(const bf16x8*)(wb + (size_t)(ct * 16 + lm) * N + x + lg * 8);
            acc[ct] = __builtin_amdgcn_mfma_f32_16x16x32_bf16(a, bf, acc[ct], 0, 0, 0);
        }
        bf16x8 wf = *(const bf16x8*)(wb + (size_t)64 * N + x + lg * 8);
        acc[4] = __builtin_amdgcn_mfma_f32_16x16x32_bf16(a, wf, acc[4], 0, 0, 0);
    }
    #pragma unroll
    for (int ct = 0; ct < 4; ++ct)
        #pragma unroll
        for (int j = 0; j < 4; ++j)
            pb[(ro + lg * 4 + j) * 66 + ct * 16 + lm] = acc[ct][j];
    if (lm == 0) {
        #pragma unroll
        for (int j = 0; j < 4; ++j) pb[(ro + lg * 4 + j) * 66 + 64] = acc[4][j];
    }
}

// ---- reduce partials u+v -> mom[b][i][col] stride 66 (chunk counts per layer) ----
__global__ void k_reduce2(const float* __restrict__ part_u, const float* __restrict__ part_v,
                          float* __restrict__ momu, float* __restrict__ momv, int chu, int chv, int B_) {
    int by = blockIdx.y;
    const float* p;
    float* m;
    int nch, b;
    if (by < B_) { b = by; p = part_u; m = momu; nch = chu; }
    else { b = by - B_; p = part_v; m = momv; nch = chv; }
    int e = blockIdx.x * 256 + threadIdx.x;
    if (e >= 64 * 65) return;
    int row = e / 65, col = e % 65;
    const float* pp = p + ((size_t)(b * nch) * 64 + row) * 66 + col;
    float s = 0.f;
    #pragma unroll 4
    for (int c = 0; c < nch; ++c)
        s += pp[(size_t)c * 64 * 66];
    m[((size_t)b * 64 + row) * 66 + col] = s;
}

// ---- transpose weights (l,i,o,k)->(l,k,i,o) ----
__global__ __launch_bounds__(256) void k_tw(const float* __restrict__ e_c, const float* __restrict__ e_s,
                                            const float* __restrict__ u_c, const float* __restrict__ u_s,
                                            const float* __restrict__ v_c, const float* __restrict__ v_s,
                                            float* __restrict__ oT) {
    int li = blockIdx.x;
    int a = blockIdx.y;
    const float* in;
    switch (a) {
        case 0: in = e_c; break;
        case 1: in = e_s; break;
        case 2: in = u_c; break;
        case 3: in = u_s; break;
        case 4: in = v_c; break;
        default: in = v_s; break;
    }
    float* outp = oT + (size_t)a * 393216;
    int l = li >> 6, i = li & 63;
    __shared__ float t[32][65];
    int tid = threadIdx.x;
    const float* ib = in + (size_t)l * 131072 + (size_t)i * 2048;
    #pragma unroll
    for (int r = 0; r < 8; ++r) {
        int e = r * 256 + tid;
        t[e & 31][e >> 5] = ib[e];
    }
    __syncthreads();
    float* ob = outp + (size_t)l * 131072 + (size_t)i * 64;
    #pragma unroll
    for (int r = 0; r < 8; ++r) {
        int e = r * 256 + tid;
        ob[(size_t)(e >> 6) * 4096 + (e & 63)] = t[e >> 6][e & 63];
    }
}

// ---- buildW -> WBf[b][o][hi128|lo128] bf16 + bias[b][o] fp32 ----
__global__ void k_buildW(const float* __restrict__ momu, const float* __restrict__ momv,
                         const float* __restrict__ ecT, const float* __restrict__ esT, const float* __restrict__ ew0,
                         const float* __restrict__ ucT, const float* __restrict__ usT, const float* __restrict__ uw0,
                         const float* __restrict__ vcT, const float* __restrict__ vsT, const float* __restrict__ vw0,
                         const float* __restrict__ wsuw, const float* __restrict__ wsub,
                         const float* __restrict__ wsvw, const float* __restrict__ wsvb,
                         unsigned short* __restrict__ WuBf, unsigned short* __restrict__ WvBf,
                         float* __restrict__ biasU, float* __restrict__ biasV, int do_v) {
    int b = blockIdx.y, j = blockIdx.x, o = threadIdx.x;
    const float* mu = momu + (size_t)b * 64 * 66;
    const float* mv = momv + (size_t)b * 64 * 66;
    unsigned short* Wub = WuBf + ((size_t)b * 64 + o) * 256;
    unsigned short* Wvb = WvBf + ((size_t)b * 64 + o) * 256;
    if (j < 32) {
        int k = j;
        const float* ec = ecT + (size_t)k * 4096;
        const float* es = esT + (size_t)k * 4096;
        const float* uc = ucT + (size_t)k * 4096;
        const float* us = usT + (size_t)k * 4096;
        const float* vc = vcT + (size_t)k * 4096;
        const float* vs = vsT + (size_t)k * 4096;
        float fcu = 0, fsu = 0, fcv = 0, fsv = 0;
        for (int i = 0; i < 64; ++i) {
            float Scv = mv[i * 66 + k], Ssv = mv[i * 66 + 32 + k];
            float Scu = mu[i * 66 + k], Ssu = mu[i * 66 + 32 + k];
            int wi = i * 64 + o;
            float e_c = ec[wi], e_s = es[wi];
            float u_c = uc[wi], u_s = us[wi];
            fcu += Scv * e_c + Ssv * e_s + Scu * u_c + Ssu * u_s;
            fsu += Scv * e_s - Ssv * e_c + Scu * u_s - Ssu * u_c;
            if (do_v) {
                float v_c = vc[wi], v_s = vs[wi];
                fcv += Scv * v_c + Ssv * v_s;
                fsv += Scv * v_s - Ssv * v_c;
            }
        }
        wsplit(2.f * fcu, Wub + k);
        wsplit(-2.f * fsu, Wub + 32 + k);
        if (do_v) {
            wsplit(2.f * fcv, Wvb + k);
            wsplit(-2.f * fsv, Wvb + 32 + k);
        }
    } else {
        for (int c = 0; c < 64; ++c) wsplit(wsuw[o * 64 + c], Wub + 64 + c);
        float f0u = 0;
        for (int i = 0; i < 64; ++i)
            f0u += mv[i * 66 + 64] * ew0[i * 64 + o] + mu[i * 66 + 64] * uw0[i * 64 + o];
        biasU[b * 64 + o] = f0u + wsub[o];
        if (do_v) {
            for (int c = 0; c < 64; ++c) wsplit(wsvw[o * 64 + c], Wvb + 64 + c);
            float f0v = 0;
            for (int i = 0; i < 64; ++i) f0v += mv[i * 66 + 64] * vw0[i * 64 + o];
            biasV[b * 64 + o] = f0v + wsvb[o];
        }
    }
}

// ---- fallback buildW (original weight layout) ----
__global__ void k_buildW_slow(const float* __restrict__ momu, const float* __restrict__ momv,
                              const float* __restrict__ ewc, const float* __restrict__ ews, const float* __restrict__ ew0,
                              const float* __restrict__ uwc, const float* __restrict__ uws, const float* __restrict__ uw0,
                              const float* __restrict__ vwc, const float* __restrict__ vws, const float* __restrict__ vw0,
                              const float* __restrict__ wsuw, const float* __restrict__ wsub,
                              const float* __restrict__ wsvw, const float* __restrict__ wsvb,
                              unsigned short* __restrict__ WuBf, unsigned short* __restrict__ WvBf,
                              float* __restrict__ biasU, float* __restrict__ biasV, int do_v) {
    int b = blockIdx.y, j = blockIdx.x, o = threadIdx.x;
    const float* mu = momu + (size_t)b * 64 * 66;
    const float* mv = momv + (size_t)b * 64 * 66;
    unsigned short* Wub = WuBf + ((size_t)b * 64 + o) * 256;
    unsigned short* Wvb = WvBf + ((size_t)b * 64 + o) * 256;
    if (j < 32) {
        int k = j;
        float fcu = 0, fsu = 0, fcv = 0, fsv = 0;
        for (int i = 0; i < 64; ++i) {
            float Scv = mv[i * 66 + k], Ssv = mv[i * 66 + 32 + k];
            float Scu = mu[i * 66 + k], Ssu = mu[i * 66 + 32 + k];
            int wi = (i * 64 + o) * 32 + k;
            float ec = ewc[wi], es = ews[wi];
            float uc = uwc[wi], us = uws[wi];
            fcu += Scv * ec + Ssv * es + Scu * uc + Ssu * us;
            fsu += Scv * es - Ssv * ec + Scu * us - Ssu * uc;
            if (do_v) {
                float vc = vwc[wi], vs = vws[wi];
                fcv += Scv * vc + Ssv * vs;
                fsv += Scv * vs - Ssv * vc;
            }
        }
        wsplit(2.f * fcu, Wub + k);
        wsplit(-2.f * fsu, Wub + 32 + k);
        if (do_v) {
            wsplit(2.f * fcv, Wvb + k);
            wsplit(-2.f * fsv, Wvb + 32 + k);
        }
    } else {
        for (int c = 0; c < 64; ++c) wsplit(wsuw[o * 64 + c], Wub + 64 + c);
        float f0u = 0;
        for (int i = 0; i < 64; ++i)
            f0u += mv[i * 66 + 64] * ew0[i * 64 + o] + mu[i * 66 + 64] * uw0[i * 64 + o];
        biasU[b * 64 + o] = f0u + wsub[o];
        if (do_v) {
            for (int c = 0; c < 64; ++c) wsplit(wsvw[o * 64 + c], Wvb + 64 + c);
            float f0v = 0;
            for (int i = 0; i < 64; ++i) f0v += mv[i * 66 + 64] * vw0[i * 64 + o];
            biasV[b * 64 + o] = f0v + wsvb[o];
        }
    }
}

// ---- fused synthesis u+v + next-layer analysis epilogue.
// Block owns 256 x-cols (2 tiles of 128). Main MFMA + direct writes (round-8 style,
// measured near-ideal WRITE_SIZE). do_mom: stage rounded tile in LDS [c][x], run
// analysis2's 5-MFMA loop vs wbb, accumulate partial moments -> part[b][blk]. ----
__global__ __launch_bounds__(256) void k_synth3(const unsigned short* __restrict__ WuBf,
                                                const unsigned short* __restrict__ WvBf,
                                                const float* __restrict__ biasU, const float* __restrict__ biasV,
                                                unsigned short* FTu, unsigned short* FTv,
                                                const unsigned short* __restrict__ wbb_u,
                                                const unsigned short* __restrict__ wbb_v,
                                                float* __restrict__ part_u, float* __restrict__ part_v,
                                                int NU_, int NV_, int nbu, int act_u, int wft_v, int do_mom) {
    int bx = blockIdx.x, b = blockIdx.y, tid = threadIdx.x;
    const unsigned short* Wb;
    const float* bi;
    unsigned short* FT;
    const unsigned short* wb;
    float* pb;
    int N, act, wft, blk;
    if (bx < nbu) {
        blk = bx; Wb = WuBf; bi = biasU; FT = FTu; N = NU_;
        wb = wbb_u + (size_t)b * 65 * NU_;
        pb = part_u + (size_t)(b * (NU_ / 256) + blk) * 64 * 66;
        act = act_u; wft = 1;
    } else {
        blk = bx - nbu; Wb = WvBf; bi = biasV; FT = FTv; N = NV_;
        wb = wbb_v + (size_t)b * 65 * NV_;
        pb = part_v + (size_t)(b * (NV_ / 256) + blk) * 64 * 66;
        act = 1; wft = wft_v;
    }
    int lane = tid & 63, wv = tid >> 6;
    int lm = lane & 15, lg = lane >> 4;
    int ro = wv * 16;
    const unsigned short* Wrow = Wb + ((size_t)b * 64 + ro + lm) * 256;
    bf16x8 ahi[4], alo[4];
    #pragma unroll
    for (int kt = 0; kt < 4; ++kt) {
        ahi[kt] = *(const bf16x8*)(Wrow + kt * 32 + lg * 8);
        alo[kt] = *(const bf16x8*)(Wrow + 128 + kt * 32 + lg * 8);
    }
    float bias[4];
    #pragma unroll
    for (int j = 0; j < 4; ++j) bias[j] = bi[b * 64 + ro + lg * 4 + j];
    unsigned short* ftb = FT + (size_t)b * N * 128;
    __shared__ unsigned short st2[64][136];
    f32x4 macc[5] = {};
    int r0 = ro + lg * 4;
    for (int t = 0; t < 2; ++t) {
        int x0 = blk * 256 + t * 128;
        f32x4 acc[8] = {};
        #pragma unroll
        for (int xt = 0; xt < 8; ++xt) {
            int x = x0 + xt * 16 + lm;
            const unsigned short* fp = ftb + (size_t)x * 128 + lg * 8;
            #pragma unroll
            for (int kt = 0; kt < 4; ++kt) {
                bf16x8 bf = *(const bf16x8*)(fp + kt * 32);
                acc[xt] = __builtin_amdgcn_mfma_f32_16x16x32_bf16(ahi[kt], bf, acc[xt], 0, 0, 0);
                acc[xt] = __builtin_amdgcn_mfma_f32_16x16x32_bf16(alo[kt], bf, acc[xt], 0, 0, 0);
            }
        }
        // barrier: (a) all FT reads of this tile done before in-place ch writes,
        // (b) previous tile's moment reads of st2 done before overwrite
        __syncthreads();
        #pragma unroll
        for (int xt = 0; xt < 8; ++xt) {
            int xl = xt * 16 + lm;
            float v[4];
            #pragma unroll
            for (int j = 0; j < 4; ++j) {
                v[j] = acc[xt][j] + bias[j];
                if (act) v[j] = gelu_f(v[j]);
            }
            unsigned short h[4];
            #pragma unroll
            for (int j = 0; j < 4; ++j) h[j] = f2bf(v[j]);
            if (do_mom) {
                st2[r0 + 0][xl] = h[0];
                st2[r0 + 1][xl] = h[1];
                st2[r0 + 2][xl] = h[2];
                st2[r0 + 3][xl] = h[3];
            }
            if (wft) {
                unsigned int* dst = (unsigned int*)(ftb + (size_t)(x0 + xl) * 128 + 64 + r0);
                dst[0] = pk(h[0], h[1]);
                dst[1] = pk(h[2], h[3]);
            }
        }
        if (do_mom) {
            __syncthreads();
            #pragma unroll
            for (int xs = 0; xs < 128; xs += 32) {
                bf16x8 a = *(const bf16x8*)&st2[ro + lm][xs + lg * 8];
                #pragma unroll
                for (int ct = 0; ct < 4; ++ct) {
                    bf16x8 bw = *(const bf16x8*)(wb + (size_t)(ct * 16 + lm) * N + x0 + xs + lg * 8);
                    macc[ct] = __builtin_amdgcn_mfma_f32_16x16x32_bf16(a, bw, macc[ct], 0, 0, 0);
                }
                bf16x8 wf = *(const bf16x8*)(wb + (size_t)64 * N + x0 + xs + lg * 8);
                macc[4] = __builtin_amdgcn_mfma_f32_16x16x32_bf16(a, wf, macc[4], 0, 0, 0);
            }
        }
    }
    if (do_mom) {
        #pragma unroll
        for (int ct = 0; ct < 4; ++ct)
            #pragma unroll
            for (int j = 0; j < 4; ++j)
                pb[(r0 + j) * 66 + ct * 16 + lm] = macc[ct][j];
        if (lm == 0) {
            #pragma unroll
            for (int j = 0; j < 4; ++j) pb[(r0 + j) * 66 + 64] = macc[4][j];
        }
    }
}

// ---- fc1(gelu)+fc2 fused, MFMA from FT ch-cols ----
__global__ __launch_bounds__(256) void k_fc12(const unsigned short* __restrict__ FT, const float* __restrict__ w1,
                                              const float* __restrict__ b1, const float* __restrict__ w2,
                                              const float* __restrict__ b2, float* __restrict__ out, int N) {
    int b = blockIdx.y, blk = blockIdx.x, tid = threadIdx.x;
    int lane = tid & 63, wv = tid >> 6;
    int lm = lane & 15, lg = lane >> 4;
    int f0 = wv * 32;
    bf16x8 ahi[2][2], alo[2][2];
    #pragma unroll
    for (int ft = 0; ft < 2; ++ft)
        #pragma unroll
        for (int kt = 0; kt < 2; ++kt) {
            const float* wp = w1 + (size_t)(f0 + ft * 16 + lm) * 64 + kt * 32 + lg * 8;
            float tmp[8];
            *(float4*)&tmp[0] = *(const float4*)wp;
            *(float4*)&tmp[4] = *(const float4*)(wp + 4);
            #pragma unroll
            for (int i = 0; i < 8; ++i) {
                unsigned short h = f2bf(tmp[i]);
                ahi[ft][kt][i] = (short)h;
                alo[ft][kt][i] = (short)f2bf(tmp[i] - bf2f(h));
            }
        }
    float b1v[2][4], w2v[2][4];
    #pragma unroll
    for (int ft = 0; ft < 2; ++ft)
        #pragma unroll
        for (int j = 0; j < 4; ++j) {
            int f = f0 + ft * 16 + lg * 4 + j;
            b1v[ft][j] = b1[f];
            w2v[ft][j] = w2[f];
        }
    f32x4 acc[8][2] = {};
    const unsigned short* ftb = FT + (size_t)b * N * 128;
    int x0 = blk * 128;
    #pragma unroll
    for (int xt = 0; xt < 8; ++xt) {
        const unsigned short* fp = ftb + (size_t)(x0 + xt * 16 + lm) * 128 + 64 + lg * 8;
        bf16x8 bf0 = *(const bf16x8*)fp;
        bf16x8 bf1 = *(const bf16x8*)(fp + 32);
        #pragma unroll
        for (int ft = 0; ft < 2; ++ft) {
            acc[xt][ft] = __builtin_amdgcn_mfma_f32_16x16x32_bf16(ahi[ft][0], bf0, acc[xt][ft], 0, 0, 0);
            acc[xt][ft] = __builtin_amdgcn_mfma_f32_16x16x32_bf16(alo[ft][0], bf0, acc[xt][ft], 0, 0, 0);
            acc[xt][ft] = __builtin_amdgcn_mfma_f32_16x16x32_bf16(ahi[ft][1], bf1, acc[xt][ft], 0, 0, 0);
            acc[xt][ft] = __builtin_amdgcn_mfma_f32_16x16x32_bf16(alo[ft][1], bf1, acc[xt][ft], 0, 0, 0);
        }
    }
    __shared__ float red[4][8][16];
    #pragma unroll
    for (int xt = 0; xt < 8; ++xt) {
        float s = 0.f;
        #pragma unroll
        for (int ft = 0; ft < 2; ++ft)
            #pragma unroll
            for (int j = 0; j < 4; ++j) {
                float v = acc[xt][ft][j] + b1v[ft][j];
                s += w2v[ft][j] * gelu_f(v);
            }
        s += __shfl_xor(s, 16, 64);
        s += __shfl_xor(s, 32, 64);
        if (lg == 0) red[wv][xt][lm] = s;
    }
    __syncthreads();
    if (tid < 128) {
        int xt = tid >> 4, lmm = tid & 15;
        float s = b2[0] + red[0][xt][lmm] + red[1][xt][lmm] + red[2][xt][lmm] + red[3][xt][lmm];
        out[(size_t)b * N + x0 + tid] = s;
    }
}

extern "C" void kernel_launch(void* const* d_in, const int* in_sizes, int n_in,
                              void* d_out, int out_size, void* d_ws, size_t ws_size,
                              hipStream_t stream) {
    const float* u_in = (const float*)d_in[0];
    const float* v_in = (const float*)d_in[1];
    const float* nodes_u = (const float*)d_in[3];
    const float* nodes_v = (const float*)d_in[4];
    const float* nwu = (const float*)d_in[5];
    const float* nwv = (const float*)d_in[6];
    const float* modes = (const float*)d_in[7];
    const float* latent = (const float*)d_in[8];
    const float* fc0uw = (const float*)d_in[9];
    const float* fc0ub = (const float*)d_in[10];
    const float* fc0vw = (const float*)d_in[11];
    const float* fc0vb = (const float*)d_in[12];
    const float* ewc = (const float*)d_in[13];
    const float* ews = (const float*)d_in[14];
    const float* ew0 = (const float*)d_in[15];
    const float* uwc = (const float*)d_in[16];
    const float* uws = (const float*)d_in[17];
    const float* uw0 = (const float*)d_in[18];
    const float* vwc = (const float*)d_in[19];
    const float* vws = (const float*)d_in[20];
    const float* vw0 = (const float*)d_in[21];
    const float* wsuw = (const float*)d_in[22];
    const float* wsub = (const float*)d_in[23];
    const float* wsvw = (const float*)d_in[24];
    const float* wsvb = (const float*)d_in[25];
    const float* fc1w = (const float*)d_in[26];
    const float* fc1b = (const float*)d_in[27];
    const float* fc2w = (const float*)d_in[28];
    const float* fc2b = (const float*)d_in[29];
    float* out = (float*)d_out;

    const int B = 4, NU = 65536, NV = 16384;
    const int CH_U = 256, CH_V = 128;

    unsigned short* FT_u = (unsigned short*)d_ws;
    unsigned short* FT_v = FT_u + (size_t)B * NU * 128;
    unsigned short* wbb_u = FT_v + (size_t)B * NV * 128;
    unsigned short* wbb_v = wbb_u + (size_t)B * 65 * NU;
    unsigned short* chbf_u = wbb_v + (size_t)B * 65 * NV;
    unsigned short* chbf_v = chbf_u + (size_t)B * 64 * NU;
    float* part_u = (float*)(chbf_v + (size_t)B * 64 * NV);
    float* part_v = part_u + (size_t)B * CH_U * 64 * 66;
    float* momu = part_v + (size_t)B * CH_V * 64 * 66;
    float* momv = momu + B * 64 * 66;
    unsigned short* WuBf = (unsigned short*)(momv + B * 64 * 66);
    unsigned short* WvBf = WuBf + (size_t)B * 64 * 256;
    float* biasU = (float*)(WvBf + (size_t)B * 64 * 256);
    float* biasV = biasU + B * 64;
    float* wT = biasV + B * 64;
    size_t need_T = (size_t)((char*)(wT + 6 * 393216) - (char*)d_ws);
    int use_T = (ws_size >= need_T) ? 1 : 0;

    k_prep<2><<<dim3(NU / 256, B), 256, 0, stream>>>(nodes_u, modes, latent, nwu, u_in, fc0uw, fc0ub,
                                                     FT_u, wbb_u, chbf_u, NU);
    k_prep<3><<<dim3(NV / 256, B), 256, 0, stream>>>(nodes_v, modes, latent, nwv, v_in, fc0vw, fc0vb,
                                                     FT_v, wbb_v, chbf_v, NV);
    if (use_T)
        k_tw<<<dim3(192, 6), 256, 0, stream>>>(ewc, ews, uwc, uws, vwc, vws, wT);

    // analysis only for layer 0; layers 1,2 get moments from the synth epilogue
    k_analysis2<<<dim3(CH_U + CH_V, B), 256, 0, stream>>>(chbf_u, wbb_u, chbf_v, wbb_v,
                                                          part_u, part_v, NU, NV, CH_U, CH_V);

    for (int l = 0; l < 3; ++l) {
        int do_v = (l < 2) ? 1 : 0;
        int chu_l = (l == 0) ? CH_U : NU / 256;   // 256 both, kept explicit
        int chv_l = (l == 0) ? CH_V : NV / 256;   // 128 at l=0, 64 after
        k_reduce2<<<dim3(17, 2 * B), 256, 0, stream>>>(part_u, part_v, momu, momv, chu_l, chv_l, B);
        if (use_T) {
            k_buildW<<<dim3(33, B), 64, 0, stream>>>(momu, momv,
                wT + 0 * 393216 + l * 131072, wT + 1 * 393216 + l * 131072, ew0 + (size_t)l * 64 * 64,
                wT + 2 * 393216 + l * 131072, wT + 3 * 393216 + l * 131072, uw0 + (size_t)l * 64 * 64,
                wT + 4 * 393216 + l * 131072, wT + 5 * 393216 + l * 131072, vw0 + (size_t)l * 64 * 64,
                wsuw + l * 64 * 64, wsub + l * 64, wsvw + l * 64 * 64, wsvb + l * 64,
                WuBf, WvBf, biasU, biasV, do_v);
        } else {
            k_buildW_slow<<<dim3(33, B), 64, 0, stream>>>(momu, momv,
                ewc + (size_t)l * 64 * 64 * 32, ews + (size_t)l * 64 * 64 * 32, ew0 + (size_t)l * 64 * 64,
                uwc + (size_t)l * 64 * 64 * 32, uws + (size_t)l * 64 * 64 * 32, uw0 + (size_t)l * 64 * 64,
                vwc + (size_t)l * 64 * 64 * 32, vws + (size_t)l * 64 * 64 * 32, vw0 + (size_t)l * 64 * 64,
                wsuw + l * 64 * 64, wsub + l * 64, wsvw + l * 64 * 64, wsvb + l * 64,
                WuBf, WvBf, biasU, biasV, do_v);
        }
        int nbu2 = NU / 256;
        int nbx = nbu2 + (do_v ? NV / 256 : 0);
        int do_mom = (l < 2) ? 1 : 0;
        int wft_v = (l == 0) ? 1 : 0;   // FT_v ch-cols dead after last v-synth read
        k_synth3<<<dim3(nbx, B), 256, 0, stream>>>(WuBf, WvBf, biasU, biasV, FT_u, FT_v,
                                                   wbb_u, wbb_v, part_u, part_v,
                                                   NU, NV, nbu2, do_v /*act_u*/, wft_v, do_mom);
    }
    k_fc12<<<dim3(NU / 128, B), 256, 0, stream>>>(FT_u, fc1w, fc1b, fc2w, fc2b, out, NU);
}

// Round 11
// 504.767 us; speedup vs baseline: 1.1323x; 1.0413x over previous
//
#include <hip/hip_runtime.h>
#include <math.h>

#define PI2 6.283185307179586f

typedef __attribute__((ext_vector_type(8))) short bf16x8;
typedef __attribute__((ext_vector_type(4))) float f32x4;

__device__ __forceinline__ float gelu_f(float x) {
    return 0.5f * x * (1.0f + erff(x * 0.7071067811865476f));
}
__device__ __forceinline__ unsigned short f2bf(float f) {
    unsigned int u = __float_as_uint(f);
    u += 0x7FFFu + ((u >> 16) & 1u);
    return (unsigned short)(u >> 16);
}
__device__ __forceinline__ float bf2f(unsigned short h) {
    return __uint_as_float(((unsigned int)h) << 16);
}
__device__ __forceinline__ unsigned int pk(unsigned short a, unsigned short b) {
    return (unsigned int)a | ((unsigned int)b << 16);
}
__device__ __forceinline__ void wsplit(float w, unsigned short* dst) {
    unsigned short h = f2bf(w);
    dst[0] = h;
    dst[128] = f2bf(w - bf2f(h));
}

// ---- fused bases + fc0 ----
template<int NIN>
__global__ __launch_bounds__(256) void k_prep(const float* __restrict__ nodes, const float* __restrict__ modes,
                                              const float* __restrict__ latent, const float* __restrict__ nw,
                                              const float* __restrict__ inp, const float* __restrict__ fcw,
                                              const float* __restrict__ fcb,
                                              unsigned short* __restrict__ FT, unsigned short* __restrict__ wbb,
                                              unsigned short* __restrict__ chbf, int N) {
    int b = blockIdx.y;
    int x = blockIdx.x * 256 + threadIdx.x;
    float s0 = 0.5f + 1.5f / (1.0f + expf(-latent[0]));
    float s1 = 0.5f + 1.5f / (1.0f + expf(-latent[1]));
    float n0 = nodes[((size_t)b * N + x) * 2 + 0];
    float n1 = nodes[((size_t)b * N + x) * 2 + 1];
    float wx = nw[(size_t)b * N + x];
    unsigned short* wb = wbb + (size_t)b * 65 * N + x;
    unsigned int row[64];
    #pragma unroll
    for (int k = 0; k < 32; ++k) {
        float m0 = modes[k * 2 + 0] * s0;
        float m1 = modes[k * 2 + 1] * s1;
        float t = PI2 * (n0 * m0 + n1 * m1);
        float s, c;
        sincosf(t, &s, &c);
        unsigned short hc = f2bf(c), hs = f2bf(s);
        if (k & 1) { row[k >> 1] |= ((unsigned int)hc << 16); row[16 + (k >> 1)] |= ((unsigned int)hs << 16); }
        else       { row[k >> 1] = hc;                         row[16 + (k >> 1)] = hs; }
        wb[(size_t)k * N] = f2bf(c * wx);
        wb[(size_t)(32 + k) * N] = f2bf(s * wx);
    }
    wb[(size_t)64 * N] = f2bf(wx);
    float xi[NIN];
    #pragma unroll
    for (int i = 0; i < NIN; ++i) xi[i] = inp[((size_t)b * N + x) * NIN + i];
    unsigned short* cb = chbf + (size_t)b * 64 * N + x;
    #pragma unroll
    for (int c = 0; c < 64; ++c) {
        float a = fcb[c];
        #pragma unroll
        for (int i = 0; i < NIN; ++i) a += fcw[c * NIN + i] * xi[i];
        unsigned short h = f2bf(a);
        cb[(size_t)c * N] = h;
        if (c & 1) row[32 + (c >> 1)] |= ((unsigned int)h << 16);
        else row[32 + (c >> 1)] = h;
    }
    unsigned int* fr = (unsigned int*)(FT + ((size_t)b * N + x) * 128);
    #pragma unroll
    for (int i = 0; i < 64; ++i) fr[i] = row[i];
}

// ---- analysis u+v (MFMA) from chbf planes: layer-0 moments only ----
__global__ __launch_bounds__(256) void k_analysis2(const unsigned short* __restrict__ chbf_u,
                                                   const unsigned short* __restrict__ wbb_u,
                                                   const unsigned short* __restrict__ chbf_v,
                                                   const unsigned short* __restrict__ wbb_v,
                                                   float* __restrict__ part_u, float* __restrict__ part_v,
                                                   int NU_, int NV_, int chu, int chv) {
    int b = blockIdx.y, bx = blockIdx.x, tid = threadIdx.x;
    const unsigned short *chb, *wb;
    float* pb;
    int N, xlen, chunk;
    if (bx < chu) {
        chunk = bx; N = NU_; xlen = NU_ / chu;
        chb = chbf_u + (size_t)b * 64 * N;
        wb = wbb_u + (size_t)b * 65 * N;
        pb = part_u + (size_t)(b * chu + chunk) * 64 * 66;
    } else {
        chunk = bx - chu; N = NV_; xlen = NV_ / chv;
        chb = chbf_v + (size_t)b * 64 * N;
        wb = wbb_v + (size_t)b * 65 * N;
        pb = part_v + (size_t)(b * chv + chunk) * 64 * 66;
    }
    int lane = tid & 63, wv = tid >> 6;
    int lm = lane & 15, lg = lane >> 4;
    int ro = wv * 16;
    int x0 = chunk * xlen;
    f32x4 acc[5] = {};
    for (int x = x0; x < x0 + xlen; x += 32) {
        bf16x8 a = *(const bf16x8*)(chb + (size_t)(ro + lm) * N + x + lg * 8);
        #pragma unroll
        for (int ct = 0; ct < 4; ++ct) {
            bf16x8 bf = *(const bf16x8*)(wb + (size_t)(ct * 16 + lm) * N + x + lg * 8);
            acc[ct] = __builtin_amdgcn_mfma_f32_16x16x32_bf16(a, bf, acc[ct], 0, 0, 0);
        }
        bf16x8 wf = *(const bf16x8*)(wb + (size_t)64 * N + x + lg * 8);
        acc[4] = __builtin_amdgcn_mfma_f32_16x16x32_bf16(a, wf, acc[4], 0, 0, 0);
    }
    #pragma unroll
    for (int ct = 0; ct < 4; ++ct)
        #pragma unroll
        for (int j = 0; j < 4; ++j)
            pb[(ro + lg * 4 + j) * 66 + ct * 16 + lm] = acc[ct][j];
    if (lm == 0) {
        #pragma unroll
        for (int j = 0; j < 4; ++j) pb[(ro + lg * 4 + j) * 66 + 64] = acc[4][j];
    }
}

// ---- reduce partials u+v: 8 threads per output element + LDS tree ----
__global__ __launch_bounds__(256) void k_reduce2(const float* __restrict__ part_u, const float* __restrict__ part_v,
                                                 float* __restrict__ momu, float* __restrict__ momv,
                                                 int chu, int chv, int B_) {
    int by = blockIdx.y;
    const float* p;
    float* m;
    int nch, b;
    if (by < B_) { b = by; p = part_u; m = momu; nch = chu; }
    else { b = by - B_; p = part_v; m = momv; nch = chv; }
    int eg = threadIdx.x >> 3;
    int sp = threadIdx.x & 7;
    int e = blockIdx.x * 32 + eg;
    __shared__ float red[32][8];
    float s = 0.f;
    int row = 0, col = 0;
    if (e < 64 * 65) {
        row = e / 65; col = e % 65;
        const float* pp = p + ((size_t)(b * nch) * 64 + row) * 66 + col;
        for (int c = sp; c < nch; c += 8)
            s += pp[(size_t)c * 64 * 66];
    }
    red[eg][sp] = s;
    __syncthreads();
    if (sp == 0 && e < 64 * 65) {
        float t = 0.f;
        #pragma unroll
        for (int i = 0; i < 8; ++i) t += red[eg][i];
        m[((size_t)b * 64 + row) * 66 + col] = t;
    }
}

// ---- transpose weights (l,i,o,k)->(l,k,i,o) ----
__global__ __launch_bounds__(256) void k_tw(const float* __restrict__ e_c, const float* __restrict__ e_s,
                                            const float* __restrict__ u_c, const float* __restrict__ u_s,
                                            const float* __restrict__ v_c, const float* __restrict__ v_s,
                                            float* __restrict__ oT) {
    int li = blockIdx.x;
    int a = blockIdx.y;
    const float* in;
    switch (a) {
        case 0: in = e_c; break;
        case 1: in = e_s; break;
        case 2: in = u_c; break;
        case 3: in = u_s; break;
        case 4: in = v_c; break;
        default: in = v_s; break;
    }
    float* outp = oT + (size_t)a * 393216;
    int l = li >> 6, i = li & 63;
    __shared__ float t[32][65];
    int tid = threadIdx.x;
    const float* ib = in + (size_t)l * 131072 + (size_t)i * 2048;
    #pragma unroll
    for (int r = 0; r < 8; ++r) {
        int e = r * 256 + tid;
        t[e & 31][e >> 5] = ib[e];
    }
    __syncthreads();
    float* ob = outp + (size_t)l * 131072 + (size_t)i * 64;
    #pragma unroll
    for (int r = 0; r < 8; ++r) {
        int e = r * 256 + tid;
        ob[(size_t)(e >> 6) * 4096 + (e & 63)] = t[e >> 6][e & 63];
    }
}

// ---- buildW -> WBf[b][o][hi128|lo128] bf16 + bias fp32 ----
__global__ void k_buildW(const float* __restrict__ momu, const float* __restrict__ momv,
                         const float* __restrict__ ecT, const float* __restrict__ esT, const float* __restrict__ ew0,
                         const float* __restrict__ ucT, const float* __restrict__ usT, const float* __restrict__ uw0,
                         const float* __restrict__ vcT, const float* __restrict__ vsT, const float* __restrict__ vw0,
                         const float* __restrict__ wsuw, const float* __restrict__ wsub,
                         const float* __restrict__ wsvw, const float* __restrict__ wsvb,
                         unsigned short* __restrict__ WuBf, unsigned short* __restrict__ WvBf,
                         float* __restrict__ biasU, float* __restrict__ biasV, int do_v) {
    int b = blockIdx.y, j = blockIdx.x, o = threadIdx.x;
    const float* mu = momu + (size_t)b * 64 * 66;
    const float* mv = momv + (size_t)b * 64 * 66;
    unsigned short* Wub = WuBf + ((size_t)b * 64 + o) * 256;
    unsigned short* Wvb = WvBf + ((size_t)b * 64 + o) * 256;
    if (j < 32) {
        int k = j;
        const float* ec = ecT + (size_t)k * 4096;
        const float* es = esT + (size_t)k * 4096;
        const float* uc = ucT + (size_t)k * 4096;
        const float* us = usT + (size_t)k * 4096;
        const float* vc = vcT + (size_t)k * 4096;
        const float* vs = vsT + (size_t)k * 4096;
        float fcu = 0, fsu = 0, fcv = 0, fsv = 0;
        for (int i = 0; i < 64; ++i) {
            float Scv = mv[i * 66 + k], Ssv = mv[i * 66 + 32 + k];
            float Scu = mu[i * 66 + k], Ssu = mu[i * 66 + 32 + k];
            int wi = i * 64 + o;
            float e_c = ec[wi], e_s = es[wi];
            float u_c = uc[wi], u_s = us[wi];
            fcu += Scv * e_c + Ssv * e_s + Scu * u_c + Ssu * u_s;
            fsu += Scv * e_s - Ssv * e_c + Scu * u_s - Ssu * u_c;
            if (do_v) {
                float v_c = vc[wi], v_s = vs[wi];
                fcv += Scv * v_c + Ssv * v_s;
                fsv += Scv * v_s - Ssv * v_c;
            }
        }
        wsplit(2.f * fcu, Wub + k);
        wsplit(-2.f * fsu, Wub + 32 + k);
        if (do_v) {
            wsplit(2.f * fcv, Wvb + k);
            wsplit(-2.f * fsv, Wvb + 32 + k);
        }
    } else {
        for (int c = 0; c < 64; ++c) wsplit(wsuw[o * 64 + c], Wub + 64 + c);
        float f0u = 0;
        for (int i = 0; i < 64; ++i)
            f0u += mv[i * 66 + 64] * ew0[i * 64 + o] + mu[i * 66 + 64] * uw0[i * 64 + o];
        biasU[b * 64 + o] = f0u + wsub[o];
        if (do_v) {
            for (int c = 0; c < 64; ++c) wsplit(wsvw[o * 64 + c], Wvb + 64 + c);
            float f0v = 0;
            for (int i = 0; i < 64; ++i) f0v += mv[i * 66 + 64] * vw0[i * 64 + o];
            biasV[b * 64 + o] = f0v + wsvb[o];
        }
    }
}

// ---- fallback buildW (original layout) ----
__global__ void k_buildW_slow(const float* __restrict__ momu, const float* __restrict__ momv,
                              const float* __restrict__ ewc, const float* __restrict__ ews, const float* __restrict__ ew0,
                              const float* __restrict__ uwc, const float* __restrict__ uws, const float* __restrict__ uw0,
                              const float* __restrict__ vwc, const float* __restrict__ vws, const float* __restrict__ vw0,
                              const float* __restrict__ wsuw, const float* __restrict__ wsub,
                              const float* __restrict__ wsvw, const float* __restrict__ wsvb,
                              unsigned short* __restrict__ WuBf, unsigned short* __restrict__ WvBf,
                              float* __restrict__ biasU, float* __restrict__ biasV, int do_v) {
    int b = blockIdx.y, j = blockIdx.x, o = threadIdx.x;
    const float* mu = momu + (size_t)b * 64 * 66;
    const float* mv = momv + (size_t)b * 64 * 66;
    unsigned short* Wub = WuBf + ((size_t)b * 64 + o) * 256;
    unsigned short* Wvb = WvBf + ((size_t)b * 64 + o) * 256;
    if (j < 32) {
        int k = j;
        float fcu = 0, fsu = 0, fcv = 0, fsv = 0;
        for (int i = 0; i < 64; ++i) {
            float Scv = mv[i * 66 + k], Ssv = mv[i * 66 + 32 + k];
            float Scu = mu[i * 66 + k], Ssu = mu[i * 66 + 32 + k];
            int wi = (i * 64 + o) * 32 + k;
            float ec = ewc[wi], es = ews[wi];
            float uc = uwc[wi], us = uws[wi];
            fcu += Scv * ec + Ssv * es + Scu * uc + Ssu * us;
            fsu += Scv * es - Ssv * ec + Scu * us - Ssu * uc;
            if (do_v) {
                float vc = vwc[wi], vs = vws[wi];
                fcv += Scv * vc + Ssv * vs;
                fsv += Scv * vs - Ssv * vc;
            }
        }
        wsplit(2.f * fcu, Wub + k);
        wsplit(-2.f * fsu, Wub + 32 + k);
        if (do_v) {
            wsplit(2.f * fcv, Wvb + k);
            wsplit(-2.f * fsv, Wvb + 32 + k);
        }
    } else {
        for (int c = 0; c < 64; ++c) wsplit(wsuw[o * 64 + c], Wub + 64 + c);
        float f0u = 0;
        for (int i = 0; i < 64; ++i)
            f0u += mv[i * 66 + 64] * ew0[i * 64 + o] + mu[i * 66 + 64] * uw0[i * 64 + o];
        biasU[b * 64 + o] = f0u + wsub[o];
        if (do_v) {
            for (int c = 0; c < 64; ++c) wsplit(wsvw[o * 64 + c], Wvb + 64 + c);
            float f0v = 0;
            for (int i = 0; i < 64; ++i) f0v += mv[i * 66 + 64] * vw0[i * 64 + o];
            biasV[b * 64 + o] = f0v + wsvb[o];
        }
    }
}

// ---- fused synthesis u+v + moment epilogue; 128-col tile per block ----
__global__ __launch_bounds__(256) void k_synth3(const unsigned short* __restrict__ WuBf,
                                                const unsigned short* __restrict__ WvBf,
                                                const float* __restrict__ biasU, const float* __restrict__ biasV,
                                                unsigned short* FTu, unsigned short* FTv,
                                                const unsigned short* __restrict__ wbb_u,
                                                const unsigned short* __restrict__ wbb_v,
                                                float* __restrict__ part_u, float* __restrict__ part_v,
                                                int NU_, int NV_, int nbu, int act_u, int wft_v, int do_mom) {
    int bx = blockIdx.x, b = blockIdx.y, tid = threadIdx.x;
    const unsigned short* Wb;
    const float* bi;
    unsigned short* FT;
    const unsigned short* wb;
    float* pb;
    int N, act, wft, blk;
    if (bx < nbu) {
        blk = bx; Wb = WuBf; bi = biasU; FT = FTu; N = NU_;
        wb = wbb_u + (size_t)b * 65 * NU_;
        pb = part_u + (size_t)(b * (NU_ / 128) + blk) * 64 * 66;
        act = act_u; wft = 1;
    } else {
        blk = bx - nbu; Wb = WvBf; bi = biasV; FT = FTv; N = NV_;
        wb = wbb_v + (size_t)b * 65 * NV_;
        pb = part_v + (size_t)(b * (NV_ / 128) + blk) * 64 * 66;
        act = 1; wft = wft_v;
    }
    int lane = tid & 63, wv = tid >> 6;
    int lm = lane & 15, lg = lane >> 4;
    int ro = wv * 16;
    const unsigned short* Wrow = Wb + ((size_t)b * 64 + ro + lm) * 256;
    bf16x8 ahi[4], alo[4];
    #pragma unroll
    for (int kt = 0; kt < 4; ++kt) {
        ahi[kt] = *(const bf16x8*)(Wrow + kt * 32 + lg * 8);
        alo[kt] = *(const bf16x8*)(Wrow + 128 + kt * 32 + lg * 8);
    }
    float bias[4];
    #pragma unroll
    for (int j = 0; j < 4; ++j) bias[j] = bi[b * 64 + ro + lg * 4 + j];
    unsigned short* ftb = FT + (size_t)b * N * 128;
    __shared__ unsigned short st2[64][136];
    int r0 = ro + lg * 4;
    int x0 = blk * 128;
    f32x4 acc[8] = {};
    #pragma unroll
    for (int xt = 0; xt < 8; ++xt) {
        int x = x0 + xt * 16 + lm;
        const unsigned short* fp = ftb + (size_t)x * 128 + lg * 8;
        #pragma unroll
        for (int kt = 0; kt < 4; ++kt) {
            bf16x8 bf = *(const bf16x8*)(fp + kt * 32);
            acc[xt] = __builtin_amdgcn_mfma_f32_16x16x32_bf16(ahi[kt], bf, acc[xt], 0, 0, 0);
            acc[xt] = __builtin_amdgcn_mfma_f32_16x16x32_bf16(alo[kt], bf, acc[xt], 0, 0, 0);
        }
    }
    __syncthreads();  // all FT reads complete before in-place ch writes
    #pragma unroll
    for (int xt = 0; xt < 8; ++xt) {
        int xl = xt * 16 + lm;
        float v[4];
        #pragma unroll
        for (int j = 0; j < 4; ++j) {
            v[j] = acc[xt][j] + bias[j];
            if (act) v[j] = gelu_f(v[j]);
        }
        unsigned short h[4];
        #pragma unroll
        for (int j = 0; j < 4; ++j) h[j] = f2bf(v[j]);
        if (do_mom) {
            st2[r0 + 0][xl] = h[0];
            st2[r0 + 1][xl] = h[1];
            st2[r0 + 2][xl] = h[2];
            st2[r0 + 3][xl] = h[3];
        }
        if (wft) {
            unsigned int* dst = (unsigned int*)(ftb + (size_t)(x0 + xl) * 128 + 64 + r0);
            dst[0] = pk(h[0], h[1]);
            dst[1] = pk(h[2], h[3]);
        }
    }
    if (do_mom) {
        __syncthreads();  // st2 visible to moment phase
        f32x4 macc[5] = {};
        #pragma unroll
        for (int xs = 0; xs < 128; xs += 32) {
            bf16x8 a = *(const bf16x8*)&st2[ro + lm][xs + lg * 8];
            #pragma unroll
            for (int ct = 0; ct < 4; ++ct) {
                bf16x8 bw = *(const bf16x8*)(wb + (size_t)(ct * 16 + lm) * N + x0 + xs + lg * 8);
                macc[ct] = __builtin_amdgcn_mfma_f32_16x16x32_bf16(a, bw, macc[ct], 0, 0, 0);
            }
            bf16x8 wf = *(const bf16x8*)(wb + (size_t)64 * N + x0 + xs + lg * 8);
            macc[4] = __builtin_amdgcn_mfma_f32_16x16x32_bf16(a, wf, macc[4], 0, 0, 0);
        }
        #pragma unroll
        for (int ct = 0; ct < 4; ++ct)
            #pragma unroll
            for (int j = 0; j < 4; ++j)
                pb[(r0 + j) * 66 + ct * 16 + lm] = macc[ct][j];
        if (lm == 0) {
            #pragma unroll
            for (int j = 0; j < 4; ++j) pb[(r0 + j) * 66 + 64] = macc[4][j];
        }
    }
}

// ---- fc1(gelu)+fc2 fused, MFMA from FT ch-cols ----
__global__ __launch_bounds__(256) void k_fc12(const unsigned short* __restrict__ FT, const float* __restrict__ w1,
                                              const float* __restrict__ b1, const float* __restrict__ w2,
                                              const float* __restrict__ b2, float* __restrict__ out, int N) {
    int b = blockIdx.y, blk = blockIdx.x, tid = threadIdx.x;
    int lane = tid & 63, wv = tid >> 6;
    int lm = lane & 15, lg = lane >> 4;
    int f0 = wv * 32;
    bf16x8 ahi[2][2], alo[2][2];
    #pragma unroll
    for (int ft = 0; ft < 2; ++ft)
        #pragma unroll
        for (int kt = 0; kt < 2; ++kt) {
            const float* wp = w1 + (size_t)(f0 + ft * 16 + lm) * 64 + kt * 32 + lg * 8;
            float tmp[8];
            *(float4*)&tmp[0] = *(const float4*)wp;
            *(float4*)&tmp[4] = *(const float4*)(wp + 4);
            #pragma unroll
            for (int i = 0; i < 8; ++i) {
                unsigned short h = f2bf(tmp[i]);
                ahi[ft][kt][i] = (short)h;
                alo[ft][kt][i] = (short)f2bf(tmp[i] - bf2f(h));
            }
        }
    float b1v[2][4], w2v[2][4];
    #pragma unroll
    for (int ft = 0; ft < 2; ++ft)
        #pragma unroll
        for (int j = 0; j < 4; ++j) {
            int f = f0 + ft * 16 + lg * 4 + j;
            b1v[ft][j] = b1[f];
            w2v[ft][j] = w2[f];
        }
    f32x4 acc[8][2] = {};
    const unsigned short* ftb = FT + (size_t)b * N * 128;
    int x0 = blk * 128;
    #pragma unroll
    for (int xt = 0; xt < 8; ++xt) {
        const unsigned short* fp = ftb + (size_t)(x0 + xt * 16 + lm) * 128 + 64 + lg * 8;
        bf16x8 bf0 = *(const bf16x8*)fp;
        bf16x8 bf1 = *(const bf16x8*)(fp + 32);
        #pragma unroll
        for (int ft = 0; ft < 2; ++ft) {
            acc[xt][ft] = __builtin_amdgcn_mfma_f32_16x16x32_bf16(ahi[ft][0], bf0, acc[xt][ft], 0, 0, 0);
            acc[xt][ft] = __builtin_amdgcn_mfma_f32_16x16x32_bf16(alo[ft][0], bf0, acc[xt][ft], 0, 0, 0);
            acc[xt][ft] = __builtin_amdgcn_mfma_f32_16x16x32_bf16(ahi[ft][1], bf1, acc[xt][ft], 0, 0, 0);
            acc[xt][ft] = __builtin_amdgcn_mfma_f32_16x16x32_bf16(alo[ft][1], bf1, acc[xt][ft], 0, 0, 0);
        }
    }
    __shared__ float red[4][8][16];
    #pragma unroll
    for (int xt = 0; xt < 8; ++xt) {
        float s = 0.f;
        #pragma unroll
        for (int ft = 0; ft < 2; ++ft)
            #pragma unroll
            for (int j = 0; j < 4; ++j) {
                float v = acc[xt][ft][j] + b1v[ft][j];
                s += w2v[ft][j] * gelu_f(v);
            }
        s += __shfl_xor(s, 16, 64);
        s += __shfl_xor(s, 32, 64);
        if (lg == 0) red[wv][xt][lm] = s;
    }
    __syncthreads();
    if (tid < 128) {
        int xt = tid >> 4, lmm = tid & 15;
        float s = b2[0] + red[0][xt][lmm] + red[1][xt][lmm] + red[2][xt][lmm] + red[3][xt][lmm];
        out[(size_t)b * N + x0 + tid] = s;
    }
}

extern "C" void kernel_launch(void* const* d_in, const int* in_sizes, int n_in,
                              void* d_out, int out_size, void* d_ws, size_t ws_size,
                              hipStream_t stream) {
    const float* u_in = (const float*)d_in[0];
    const float* v_in = (const float*)d_in[1];
    const float* nodes_u = (const float*)d_in[3];
    const float* nodes_v = (const float*)d_in[4];
    const float* nwu = (const float*)d_in[5];
    const float* nwv = (const float*)d_in[6];
    const float* modes = (const float*)d_in[7];
    const float* latent = (const float*)d_in[8];
    const float* fc0uw = (const float*)d_in[9];
    const float* fc0ub = (const float*)d_in[10];
    const float* fc0vw = (const float*)d_in[11];
    const float* fc0vb = (const float*)d_in[12];
    const float* ewc = (const float*)d_in[13];
    const float* ews = (const float*)d_in[14];
    const float* ew0 = (const float*)d_in[15];
    const float* uwc = (const float*)d_in[16];
    const float* uws = (const float*)d_in[17];
    const float* uw0 = (const float*)d_in[18];
    const float* vwc = (const float*)d_in[19];
    const float* vws = (const float*)d_in[20];
    const float* vw0 = (const float*)d_in[21];
    const float* wsuw = (const float*)d_in[22];
    const float* wsub = (const float*)d_in[23];
    const float* wsvw = (const float*)d_in[24];
    const float* wsvb = (const float*)d_in[25];
    const float* fc1w = (const float*)d_in[26];
    const float* fc1b = (const float*)d_in[27];
    const float* fc2w = (const float*)d_in[28];
    const float* fc2b = (const float*)d_in[29];
    float* out = (float*)d_out;

    const int B = 4, NU = 65536, NV = 16384;
    const int CH_U0 = 256, CH_V0 = 128;          // layer-0 analysis chunks
    const int CH_UL = NU / 128, CH_VL = NV / 128; // 512 / 128 synth-moment chunks

    unsigned short* FT_u = (unsigned short*)d_ws;
    unsigned short* FT_v = FT_u + (size_t)B * NU * 128;
    unsigned short* wbb_u = FT_v + (size_t)B * NV * 128;
    unsigned short* wbb_v = wbb_u + (size_t)B * 65 * NU;
    unsigned short* chbf_u = wbb_v + (size_t)B * 65 * NV;
    unsigned short* chbf_v = chbf_u + (size_t)B * 64 * NU;
    float* slotA = (float*)(chbf_v + (size_t)B * 64 * NV);     // 256-chunk u partials
    float* slotB = slotA + (size_t)B * CH_U0 * 64 * 66;        // 128-chunk v partials
    float* momu = slotB + (size_t)B * CH_V0 * 64 * 66;
    float* momv = momu + B * 64 * 66;
    unsigned short* WuBf = (unsigned short*)(momv + B * 64 * 66);
    unsigned short* WvBf = WuBf + (size_t)B * 64 * 256;
    float* biasU = (float*)(WvBf + (size_t)B * 64 * 256);
    float* biasV = biasU + B * 64;
    float* wT = biasV + B * 64;
    size_t need_T = (size_t)((char*)(wT + 6 * 393216) - (char*)d_ws);
    int use_T = (ws_size >= need_T) ? 1 : 0;

    // l=0 partials: slotA/slotB.  l>=1 partials: alias dead chbf region (u) + slotA (v).
    // Safe by stream order: chbf last read by k_analysis2; slotA last read by reduce2(l=0).
    float* part0_u = slotA;
    float* part0_v = slotB;
    float* partL_u = (float*)chbf_u;   // 512 chunks * 4 * 64*66*4B = 34.6MB <= chbf_u+chbf_v (41.9MB)
    float* partL_v = slotA;            // 128 chunks fits in 256-chunk slot

    k_prep<2><<<dim3(NU / 256, B), 256, 0, stream>>>(nodes_u, modes, latent, nwu, u_in, fc0uw, fc0ub,
                                                     FT_u, wbb_u, chbf_u, NU);
    k_prep<3><<<dim3(NV / 256, B), 256, 0, stream>>>(nodes_v, modes, latent, nwv, v_in, fc0vw, fc0vb,
                                                     FT_v, wbb_v, chbf_v, NV);
    if (use_T)
        k_tw<<<dim3(192, 6), 256, 0, stream>>>(ewc, ews, uwc, uws, vwc, vws, wT);

    k_analysis2<<<dim3(CH_U0 + CH_V0, B), 256, 0, stream>>>(chbf_u, wbb_u, chbf_v, wbb_v,
                                                            part0_u, part0_v, NU, NV, CH_U0, CH_V0);

    for (int l = 0; l < 3; ++l) {
        int do_v = (l < 2) ? 1 : 0;
        const float* ru = (l == 0) ? part0_u : partL_u;
        const float* rv = (l == 0) ? part0_v : partL_v;
        int chu_l = (l == 0) ? CH_U0 : CH_UL;
        int chv_l = (l == 0) ? CH_V0 : CH_VL;
        k_reduce2<<<dim3(130, 2 * B), 256, 0, stream>>>(ru, rv, momu, momv, chu_l, chv_l, B);
        if (use_T) {
            k_buildW<<<dim3(33, B), 64, 0, stream>>>(momu, momv,
                wT + 0 * 393216 + l * 131072, wT + 1 * 393216 + l * 131072, ew0 + (size_t)l * 64 * 64,
                wT + 2 * 393216 + l * 131072, wT + 3 * 393216 + l * 131072, uw0 + (size_t)l * 64 * 64,
                wT + 4 * 393216 + l * 131072, wT + 5 * 393216 + l * 131072, vw0 + (size_t)l * 64 * 64,
                wsuw + l * 64 * 64, wsub + l * 64, wsvw + l * 64 * 64, wsvb + l * 64,
                WuBf, WvBf, biasU, biasV, do_v);
        } else {
            k_buildW_slow<<<dim3(33, B), 64, 0, stream>>>(momu, momv,
                ewc + (size_t)l * 64 * 64 * 32, ews + (size_t)l * 64 * 64 * 32, ew0 + (size_t)l * 64 * 64,
                uwc + (size_t)l * 64 * 64 * 32, uws + (size_t)l * 64 * 64 * 32, uw0 + (size_t)l * 64 * 64,
                vwc + (size_t)l * 64 * 64 * 32, vws + (size_t)l * 64 * 64 * 32, vw0 + (size_t)l * 64 * 64,
                wsuw + l * 64 * 64, wsub + l * 64, wsvw + l * 64 * 64, wsvb + l * 64,
                WuBf, WvBf, biasU, biasV, do_v);
        }
        int nbu = NU / 128;
        int nbx = nbu + (do_v ? NV / 128 : 0);
        int do_mom = (l < 2) ? 1 : 0;
        int wft_v = (l == 0) ? 1 : 0;
        k_synth3<<<dim3(nbx, B), 256, 0, stream>>>(WuBf, WvBf, biasU, biasV, FT_u, FT_v,
                                                   wbb_u, wbb_v, partL_u, partL_v,
                                                   NU, NV, nbu, do_v /*act_u*/, wft_v, do_mom);
    }
    k_fc12<<<dim3(NU / 128, B), 256, 0, stream>>>(FT_u, fc1w, fc1b, fc2w, fc2b, out, NU);
}

// Round 12
// 482.626 us; speedup vs baseline: 1.1843x; 1.0459x over previous
//
#include <hip/hip_runtime.h>
#include <math.h>

#define PI2 6.283185307179586f

typedef __attribute__((ext_vector_type(8))) short bf16x8;
typedef __attribute__((ext_vector_type(4))) float f32x4;

__device__ __forceinline__ float gelu_f(float x) {
    return 0.5f * x * (1.0f + erff(x * 0.7071067811865476f));
}
__device__ __forceinline__ unsigned short f2bf(float f) {
    unsigned int u = __float_as_uint(f);
    u += 0x7FFFu + ((u >> 16) & 1u);
    return (unsigned short)(u >> 16);
}
__device__ __forceinline__ float bf2f(unsigned short h) {
    return __uint_as_float(((unsigned int)h) << 16);
}
__device__ __forceinline__ unsigned int pk(unsigned short a, unsigned short b) {
    return (unsigned int)a | ((unsigned int)b << 16);
}
__device__ __forceinline__ void wsplit(float w, unsigned short* dst) {
    unsigned short h = f2bf(w);
    dst[0] = h;
    dst[128] = f2bf(w - bf2f(h));
}

// ---- fused bases + fc0 + layer-0 analysis.
// Block = 128 x-cols, 256 threads (tid>>7 = half; each half does 16 modes + 32 channels).
// Stages bf16 ch/weighted-bases tiles in LDS, then runs the 5-MFMA moment loop.
// Outputs: FT[b][x][128], wbb planes, partial moments part[b][chunk]. No chbf. ----
template<int NIN>
__global__ __launch_bounds__(256) void k_prep(const float* __restrict__ nodes, const float* __restrict__ modes,
                                              const float* __restrict__ latent, const float* __restrict__ nw,
                                              const float* __restrict__ inp, const float* __restrict__ fcw,
                                              const float* __restrict__ fcb,
                                              unsigned short* __restrict__ FT, unsigned short* __restrict__ wbb,
                                              float* __restrict__ part, int N) {
    int b = blockIdx.y;
    int tid = threadIdx.x;
    int xl = tid & 127, half = tid >> 7;
    int x = blockIdx.x * 128 + xl;
    __shared__ unsigned short st_c[64][136];
    __shared__ unsigned short st_w[65][136];
    float s0 = 0.5f + 1.5f / (1.0f + expf(-latent[0]));
    float s1 = 0.5f + 1.5f / (1.0f + expf(-latent[1]));
    float n0 = nodes[((size_t)b * N + x) * 2 + 0];
    float n1 = nodes[((size_t)b * N + x) * 2 + 1];
    float wx = nw[(size_t)b * N + x];
    unsigned short* wb = wbb + (size_t)b * 65 * N + x;
    unsigned int fcos[8], fsin[8], fch[16];
    #pragma unroll
    for (int kk = 0; kk < 16; ++kk) {
        int k = half * 16 + kk;
        float m0 = modes[k * 2 + 0] * s0;
        float m1 = modes[k * 2 + 1] * s1;
        float t = PI2 * (n0 * m0 + n1 * m1);
        float s, c;
        sincosf(t, &s, &c);
        unsigned short hc = f2bf(c), hs = f2bf(s);
        if (kk & 1) { fcos[kk >> 1] |= ((unsigned int)hc << 16); fsin[kk >> 1] |= ((unsigned int)hs << 16); }
        else        { fcos[kk >> 1] = hc;                         fsin[kk >> 1] = hs; }
        unsigned short hcw = f2bf(c * wx), hsw = f2bf(s * wx);
        st_w[k][xl] = hcw;
        st_w[32 + k][xl] = hsw;
        wb[(size_t)k * N] = hcw;
        wb[(size_t)(32 + k) * N] = hsw;
    }
    if (half) {
        unsigned short hw = f2bf(wx);
        st_w[64][xl] = hw;
        wb[(size_t)64 * N] = hw;
    }
    float xi[NIN];
    #pragma unroll
    for (int i = 0; i < NIN; ++i) xi[i] = inp[((size_t)b * N + x) * NIN + i];
    #pragma unroll
    for (int cc = 0; cc < 32; ++cc) {
        int c = half * 32 + cc;
        float a = fcb[c];
        #pragma unroll
        for (int i = 0; i < NIN; ++i) a += fcw[c * NIN + i] * xi[i];
        unsigned short h = f2bf(a);
        st_c[c][xl] = h;
        if (cc & 1) fch[cc >> 1] |= ((unsigned int)h << 16);
        else fch[cc >> 1] = h;
    }
    unsigned int* fr = (unsigned int*)(FT + ((size_t)b * N + x) * 128);
    #pragma unroll
    for (int i = 0; i < 8; ++i) fr[half * 8 + i] = fcos[i];
    #pragma unroll
    for (int i = 0; i < 8; ++i) fr[16 + half * 8 + i] = fsin[i];
    #pragma unroll
    for (int i = 0; i < 16; ++i) fr[32 + half * 16 + i] = fch[i];
    __syncthreads();
    // ---- moment MFMA phase (identical operand sourcing to old k_analysis2) ----
    int lane = tid & 63, wv = tid >> 6;
    int lm = lane & 15, lg = lane >> 4;
    int ro = wv * 16;
    f32x4 acc[5] = {};
    #pragma unroll
    for (int xs = 0; xs < 128; xs += 32) {
        bf16x8 a = *(const bf16x8*)&st_c[ro + lm][xs + lg * 8];
        #pragma unroll
        for (int ct = 0; ct < 4; ++ct) {
            bf16x8 bw = *(const bf16x8*)&st_w[ct * 16 + lm][xs + lg * 8];
            acc[ct] = __builtin_amdgcn_mfma_f32_16x16x32_bf16(a, bw, acc[ct], 0, 0, 0);
        }
        bf16x8 wf = *(const bf16x8*)&st_w[64][xs + lg * 8];
        acc[4] = __builtin_amdgcn_mfma_f32_16x16x32_bf16(a, wf, acc[4], 0, 0, 0);
    }
    float* pb = part + (size_t)(b * (N / 128) + blockIdx.x) * 64 * 66;
    #pragma unroll
    for (int ct = 0; ct < 4; ++ct)
        #pragma unroll
        for (int j = 0; j < 4; ++j)
            pb[(ro + lg * 4 + j) * 66 + ct * 16 + lm] = acc[ct][j];
    if (lm == 0) {
        #pragma unroll
        for (int j = 0; j < 4; ++j) pb[(ro + lg * 4 + j) * 66 + 64] = acc[4][j];
    }
}

// ---- reduce partials u+v: 8 threads per output element + LDS tree ----
__global__ __launch_bounds__(256) void k_reduce2(const float* __restrict__ part_u, const float* __restrict__ part_v,
                                                 float* __restrict__ momu, float* __restrict__ momv,
                                                 int chu, int chv, int B_) {
    int by = blockIdx.y;
    const float* p;
    float* m;
    int nch, b;
    if (by < B_) { b = by; p = part_u; m = momu; nch = chu; }
    else { b = by - B_; p = part_v; m = momv; nch = chv; }
    int eg = threadIdx.x >> 3;
    int sp = threadIdx.x & 7;
    int e = blockIdx.x * 32 + eg;
    __shared__ float red[32][8];
    float s = 0.f;
    int row = 0, col = 0;
    if (e < 64 * 65) {
        row = e / 65; col = e % 65;
        const float* pp = p + ((size_t)(b * nch) * 64 + row) * 66 + col;
        for (int c = sp; c < nch; c += 8)
            s += pp[(size_t)c * 64 * 66];
    }
    red[eg][sp] = s;
    __syncthreads();
    if (sp == 0 && e < 64 * 65) {
        float t = 0.f;
        #pragma unroll
        for (int i = 0; i < 8; ++i) t += red[eg][i];
        m[((size_t)b * 64 + row) * 66 + col] = t;
    }
}

// ---- transpose weights (l,i,o,k)->(l,k,i,o) ----
__global__ __launch_bounds__(256) void k_tw(const float* __restrict__ e_c, const float* __restrict__ e_s,
                                            const float* __restrict__ u_c, const float* __restrict__ u_s,
                                            const float* __restrict__ v_c, const float* __restrict__ v_s,
                                            float* __restrict__ oT) {
    int li = blockIdx.x;
    int a = blockIdx.y;
    const float* in;
    switch (a) {
        case 0: in = e_c; break;
        case 1: in = e_s; break;
        case 2: in = u_c; break;
        case 3: in = u_s; break;
        case 4: in = v_c; break;
        default: in = v_s; break;
    }
    float* outp = oT + (size_t)a * 393216;
    int l = li >> 6, i = li & 63;
    __shared__ float t[32][65];
    int tid = threadIdx.x;
    const float* ib = in + (size_t)l * 131072 + (size_t)i * 2048;
    #pragma unroll
    for (int r = 0; r < 8; ++r) {
        int e = r * 256 + tid;
        t[e & 31][e >> 5] = ib[e];
    }
    __syncthreads();
    float* ob = outp + (size_t)l * 131072 + (size_t)i * 64;
    #pragma unroll
    for (int r = 0; r < 8; ++r) {
        int e = r * 256 + tid;
        ob[(size_t)(e >> 6) * 4096 + (e & 63)] = t[e >> 6][e & 63];
    }
}

// ---- buildW -> WBf[b][o][hi128|lo128] bf16 + bias fp32 ----
__global__ void k_buildW(const float* __restrict__ momu, const float* __restrict__ momv,
                         const float* __restrict__ ecT, const float* __restrict__ esT, const float* __restrict__ ew0,
                         const float* __restrict__ ucT, const float* __restrict__ usT, const float* __restrict__ uw0,
                         const float* __restrict__ vcT, const float* __restrict__ vsT, const float* __restrict__ vw0,
                         const float* __restrict__ wsuw, const float* __restrict__ wsub,
                         const float* __restrict__ wsvw, const float* __restrict__ wsvb,
                         unsigned short* __restrict__ WuBf, unsigned short* __restrict__ WvBf,
                         float* __restrict__ biasU, float* __restrict__ biasV, int do_v) {
    int b = blockIdx.y, j = blockIdx.x, o = threadIdx.x;
    const float* mu = momu + (size_t)b * 64 * 66;
    const float* mv = momv + (size_t)b * 64 * 66;
    unsigned short* Wub = WuBf + ((size_t)b * 64 + o) * 256;
    unsigned short* Wvb = WvBf + ((size_t)b * 64 + o) * 256;
    if (j < 32) {
        int k = j;
        const float* ec = ecT + (size_t)k * 4096;
        const float* es = esT + (size_t)k * 4096;
        const float* uc = ucT + (size_t)k * 4096;
        const float* us = usT + (size_t)k * 4096;
        const float* vc = vcT + (size_t)k * 4096;
        const float* vs = vsT + (size_t)k * 4096;
        float fcu = 0, fsu = 0, fcv = 0, fsv = 0;
        for (int i = 0; i < 64; ++i) {
            float Scv = mv[i * 66 + k], Ssv = mv[i * 66 + 32 + k];
            float Scu = mu[i * 66 + k], Ssu = mu[i * 66 + 32 + k];
            int wi = i * 64 + o;
            float e_c = ec[wi], e_s = es[wi];
            float u_c = uc[wi], u_s = us[wi];
            fcu += Scv * e_c + Ssv * e_s + Scu * u_c + Ssu * u_s;
            fsu += Scv * e_s - Ssv * e_c + Scu * u_s - Ssu * u_c;
            if (do_v) {
                float v_c = vc[wi], v_s = vs[wi];
                fcv += Scv * v_c + Ssv * v_s;
                fsv += Scv * v_s - Ssv * v_c;
            }
        }
        wsplit(2.f * fcu, Wub + k);
        wsplit(-2.f * fsu, Wub + 32 + k);
        if (do_v) {
            wsplit(2.f * fcv, Wvb + k);
            wsplit(-2.f * fsv, Wvb + 32 + k);
        }
    } else {
        for (int c = 0; c < 64; ++c) wsplit(wsuw[o * 64 + c], Wub + 64 + c);
        float f0u = 0;
        for (int i = 0; i < 64; ++i)
            f0u += mv[i * 66 + 64] * ew0[i * 64 + o] + mu[i * 66 + 64] * uw0[i * 64 + o];
        biasU[b * 64 + o] = f0u + wsub[o];
        if (do_v) {
            for (int c = 0; c < 64; ++c) wsplit(wsvw[o * 64 + c], Wvb + 64 + c);
            float f0v = 0;
            for (int i = 0; i < 64; ++i) f0v += mv[i * 66 + 64] * vw0[i * 64 + o];
            biasV[b * 64 + o] = f0v + wsvb[o];
        }
    }
}

// ---- fallback buildW (original layout) ----
__global__ void k_buildW_slow(const float* __restrict__ momu, const float* __restrict__ momv,
                              const float* __restrict__ ewc, const float* __restrict__ ews, const float* __restrict__ ew0,
                              const float* __restrict__ uwc, const float* __restrict__ uws, const float* __restrict__ uw0,
                              const float* __restrict__ vwc, const float* __restrict__ vws, const float* __restrict__ vw0,
                              const float* __restrict__ wsuw, const float* __restrict__ wsub,
                              const float* __restrict__ wsvw, const float* __restrict__ wsvb,
                              unsigned short* __restrict__ WuBf, unsigned short* __restrict__ WvBf,
                              float* __restrict__ biasU, float* __restrict__ biasV, int do_v) {
    int b = blockIdx.y, j = blockIdx.x, o = threadIdx.x;
    const float* mu = momu + (size_t)b * 64 * 66;
    const float* mv = momv + (size_t)b * 64 * 66;
    unsigned short* Wub = WuBf + ((size_t)b * 64 + o) * 256;
    unsigned short* Wvb = WvBf + ((size_t)b * 64 + o) * 256;
    if (j < 32) {
        int k = j;
        float fcu = 0, fsu = 0, fcv = 0, fsv = 0;
        for (int i = 0; i < 64; ++i) {
            float Scv = mv[i * 66 + k], Ssv = mv[i * 66 + 32 + k];
            float Scu = mu[i * 66 + k], Ssu = mu[i * 66 + 32 + k];
            int wi = (i * 64 + o) * 32 + k;
            float ec = ewc[wi], es = ews[wi];
            float uc = uwc[wi], us = uws[wi];
            fcu += Scv * ec + Ssv * es + Scu * uc + Ssu * us;
            fsu += Scv * es - Ssv * ec + Scu * us - Ssu * uc;
            if (do_v) {
                float vc = vwc[wi], vs = vws[wi];
                fcv += Scv * vc + Ssv * vs;
                fsv += Scv * vs - Ssv * vc;
            }
        }
        wsplit(2.f * fcu, Wub + k);
        wsplit(-2.f * fsu, Wub + 32 + k);
        if (do_v) {
            wsplit(2.f * fcv, Wvb + k);
            wsplit(-2.f * fsv, Wvb + 32 + k);
        }
    } else {
        for (int c = 0; c < 64; ++c) wsplit(wsuw[o * 64 + c], Wub + 64 + c);
        float f0u = 0;
        for (int i = 0; i < 64; ++i)
            f0u += mv[i * 66 + 64] * ew0[i * 64 + o] + mu[i * 66 + 64] * uw0[i * 64 + o];
        biasU[b * 64 + o] = f0u + wsub[o];
        if (do_v) {
            for (int c = 0; c < 64; ++c) wsplit(wsvw[o * 64 + c], Wvb + 64 + c);
            float f0v = 0;
            for (int i = 0; i < 64; ++i) f0v += mv[i * 66 + 64] * vw0[i * 64 + o];
            biasV[b * 64 + o] = f0v + wsvb[o];
        }
    }
}

// ---- fused synthesis u+v + moment epilogue; 128-col tile per block ----
__global__ __launch_bounds__(256) void k_synth3(const unsigned short* __restrict__ WuBf,
                                                const unsigned short* __restrict__ WvBf,
                                                const float* __restrict__ biasU, const float* __restrict__ biasV,
                                                unsigned short* FTu, unsigned short* FTv,
                                                const unsigned short* __restrict__ wbb_u,
                                                const unsigned short* __restrict__ wbb_v,
                                                float* __restrict__ part_u, float* __restrict__ part_v,
                                                int NU_, int NV_, int nbu, int act_u, int wft_v, int do_mom) {
    int bx = blockIdx.x, b = blockIdx.y, tid = threadIdx.x;
    const unsigned short* Wb;
    const float* bi;
    unsigned short* FT;
    const unsigned short* wb;
    float* pb;
    int N, act, wft, blk;
    if (bx < nbu) {
        blk = bx; Wb = WuBf; bi = biasU; FT = FTu; N = NU_;
        wb = wbb_u + (size_t)b * 65 * NU_;
        pb = part_u + (size_t)(b * (NU_ / 128) + blk) * 64 * 66;
        act = act_u; wft = 1;
    } else {
        blk = bx - nbu; Wb = WvBf; bi = biasV; FT = FTv; N = NV_;
        wb = wbb_v + (size_t)b * 65 * NV_;
        pb = part_v + (size_t)(b * (NV_ / 128) + blk) * 64 * 66;
        act = 1; wft = wft_v;
    }
    int lane = tid & 63, wv = tid >> 6;
    int lm = lane & 15, lg = lane >> 4;
    int ro = wv * 16;
    const unsigned short* Wrow = Wb + ((size_t)b * 64 + ro + lm) * 256;
    bf16x8 ahi[4], alo[4];
    #pragma unroll
    for (int kt = 0; kt < 4; ++kt) {
        ahi[kt] = *(const bf16x8*)(Wrow + kt * 32 + lg * 8);
        alo[kt] = *(const bf16x8*)(Wrow + 128 + kt * 32 + lg * 8);
    }
    float bias[4];
    #pragma unroll
    for (int j = 0; j < 4; ++j) bias[j] = bi[b * 64 + ro + lg * 4 + j];
    unsigned short* ftb = FT + (size_t)b * N * 128;
    __shared__ unsigned short st2[64][136];
    int r0 = ro + lg * 4;
    int x0 = blk * 128;
    f32x4 acc[8] = {};
    #pragma unroll
    for (int xt = 0; xt < 8; ++xt) {
        int x = x0 + xt * 16 + lm;
        const unsigned short* fp = ftb + (size_t)x * 128 + lg * 8;
        #pragma unroll
        for (int kt = 0; kt < 4; ++kt) {
            bf16x8 bf = *(const bf16x8*)(fp + kt * 32);
            acc[xt] = __builtin_amdgcn_mfma_f32_16x16x32_bf16(ahi[kt], bf, acc[xt], 0, 0, 0);
            acc[xt] = __builtin_amdgcn_mfma_f32_16x16x32_bf16(alo[kt], bf, acc[xt], 0, 0, 0);
        }
    }
    __syncthreads();  // all FT reads complete before in-place ch writes
    #pragma unroll
    for (int xt = 0; xt < 8; ++xt) {
        int xl = xt * 16 + lm;
        float v[4];
        #pragma unroll
        for (int j = 0; j < 4; ++j) {
            v[j] = acc[xt][j] + bias[j];
            if (act) v[j] = gelu_f(v[j]);
        }
        unsigned short h[4];
        #pragma unroll
        for (int j = 0; j < 4; ++j) h[j] = f2bf(v[j]);
        if (do_mom) {
            st2[r0 + 0][xl] = h[0];
            st2[r0 + 1][xl] = h[1];
            st2[r0 + 2][xl] = h[2];
            st2[r0 + 3][xl] = h[3];
        }
        if (wft) {
            unsigned int* dst = (unsigned int*)(ftb + (size_t)(x0 + xl) * 128 + 64 + r0);
            dst[0] = pk(h[0], h[1]);
            dst[1] = pk(h[2], h[3]);
        }
    }
    if (do_mom) {
        __syncthreads();  // st2 visible to moment phase
        f32x4 macc[5] = {};
        #pragma unroll
        for (int xs = 0; xs < 128; xs += 32) {
            bf16x8 a = *(const bf16x8*)&st2[ro + lm][xs + lg * 8];
            #pragma unroll
            for (int ct = 0; ct < 4; ++ct) {
                bf16x8 bw = *(const bf16x8*)(wb + (size_t)(ct * 16 + lm) * N + x0 + xs + lg * 8);
                macc[ct] = __builtin_amdgcn_mfma_f32_16x16x32_bf16(a, bw, macc[ct], 0, 0, 0);
            }
            bf16x8 wf = *(const bf16x8*)(wb + (size_t)64 * N + x0 + xs + lg * 8);
            macc[4] = __builtin_amdgcn_mfma_f32_16x16x32_bf16(a, wf, macc[4], 0, 0, 0);
        }
        #pragma unroll
        for (int ct = 0; ct < 4; ++ct)
            #pragma unroll
            for (int j = 0; j < 4; ++j)
                pb[(r0 + j) * 66 + ct * 16 + lm] = macc[ct][j];
        if (lm == 0) {
            #pragma unroll
            for (int j = 0; j < 4; ++j) pb[(r0 + j) * 66 + 64] = macc[4][j];
        }
    }
}

// ---- fc1(gelu)+fc2 fused, MFMA from FT ch-cols ----
__global__ __launch_bounds__(256) void k_fc12(const unsigned short* __restrict__ FT, const float* __restrict__ w1,
                                              const float* __restrict__ b1, const float* __restrict__ w2,
                                              const float* __restrict__ b2, float* __restrict__ out, int N) {
    int b = blockIdx.y, blk = blockIdx.x, tid = threadIdx.x;
    int lane = tid & 63, wv = tid >> 6;
    int lm = lane & 15, lg = lane >> 4;
    int f0 = wv * 32;
    bf16x8 ahi[2][2], alo[2][2];
    #pragma unroll
    for (int ft = 0; ft < 2; ++ft)
        #pragma unroll
        for (int kt = 0; kt < 2; ++kt) {
            const float* wp = w1 + (size_t)(f0 + ft * 16 + lm) * 64 + kt * 32 + lg * 8;
            float tmp[8];
            *(float4*)&tmp[0] = *(const float4*)wp;
            *(float4*)&tmp[4] = *(const float4*)(wp + 4);
            #pragma unroll
            for (int i = 0; i < 8; ++i) {
                unsigned short h = f2bf(tmp[i]);
                ahi[ft][kt][i] = (short)h;
                alo[ft][kt][i] = (short)f2bf(tmp[i] - bf2f(h));
            }
        }
    float b1v[2][4], w2v[2][4];
    #pragma unroll
    for (int ft = 0; ft < 2; ++ft)
        #pragma unroll
        for (int j = 0; j < 4; ++j) {
            int f = f0 + ft * 16 + lg * 4 + j;
            b1v[ft][j] = b1[f];
            w2v[ft][j] = w2[f];
        }
    f32x4 acc[8][2] = {};
    const unsigned short* ftb = FT + (size_t)b * N * 128;
    int x0 = blk * 128;
    #pragma unroll
    for (int xt = 0; xt < 8; ++xt) {
        const unsigned short* fp = ftb + (size_t)(x0 + xt * 16 + lm) * 128 + 64 + lg * 8;
        bf16x8 bf0 = *(const bf16x8*)fp;
        bf16x8 bf1 = *(const bf16x8*)(fp + 32);
        #pragma unroll
        for (int ft = 0; ft < 2; ++ft) {
            acc[xt][ft] = __builtin_amdgcn_mfma_f32_16x16x32_bf16(ahi[ft][0], bf0, acc[xt][ft], 0, 0, 0);
            acc[xt][ft] = __builtin_amdgcn_mfma_f32_16x16x32_bf16(alo[ft][0], bf0, acc[xt][ft], 0, 0, 0);
            acc[xt][ft] = __builtin_amdgcn_mfma_f32_16x16x32_bf16(ahi[ft][1], bf1, acc[xt][ft], 0, 0, 0);
            acc[xt][ft] = __builtin_amdgcn_mfma_f32_16x16x32_bf16(alo[ft][1], bf1, acc[xt][ft], 0, 0, 0);
        }
    }
    __shared__ float red[4][8][16];
    #pragma unroll
    for (int xt = 0; xt < 8; ++xt) {
        float s = 0.f;
        #pragma unroll
        for (int ft = 0; ft < 2; ++ft)
            #pragma unroll
            for (int j = 0; j < 4; ++j) {
                float v = acc[xt][ft][j] + b1v[ft][j];
                s += w2v[ft][j] * gelu_f(v);
            }
        s += __shfl_xor(s, 16, 64);
        s += __shfl_xor(s, 32, 64);
        if (lg == 0) red[wv][xt][lm] = s;
    }
    __syncthreads();
    if (tid < 128) {
        int xt = tid >> 4, lmm = tid & 15;
        float s = b2[0] + red[0][xt][lmm] + red[1][xt][lmm] + red[2][xt][lmm] + red[3][xt][lmm];
        out[(size_t)b * N + x0 + tid] = s;
    }
}

extern "C" void kernel_launch(void* const* d_in, const int* in_sizes, int n_in,
                              void* d_out, int out_size, void* d_ws, size_t ws_size,
                              hipStream_t stream) {
    const float* u_in = (const float*)d_in[0];
    const float* v_in = (const float*)d_in[1];
    const float* nodes_u = (const float*)d_in[3];
    const float* nodes_v = (const float*)d_in[4];
    const float* nwu = (const float*)d_in[5];
    const float* nwv = (const float*)d_in[6];
    const float* modes = (const float*)d_in[7];
    const float* latent = (const float*)d_in[8];
    const float* fc0uw = (const float*)d_in[9];
    const float* fc0ub = (const float*)d_in[10];
    const float* fc0vw = (const float*)d_in[11];
    const float* fc0vb = (const float*)d_in[12];
    const float* ewc = (const float*)d_in[13];
    const float* ews = (const float*)d_in[14];
    const float* ew0 = (const float*)d_in[15];
    const float* uwc = (const float*)d_in[16];
    const float* uws = (const float*)d_in[17];
    const float* uw0 = (const float*)d_in[18];
    const float* vwc = (const float*)d_in[19];
    const float* vws = (const float*)d_in[20];
    const float* vw0 = (const float*)d_in[21];
    const float* wsuw = (const float*)d_in[22];
    const float* wsub = (const float*)d_in[23];
    const float* wsvw = (const float*)d_in[24];
    const float* wsvb = (const float*)d_in[25];
    const float* fc1w = (const float*)d_in[26];
    const float* fc1b = (const float*)d_in[27];
    const float* fc2w = (const float*)d_in[28];
    const float* fc2b = (const float*)d_in[29];
    float* out = (float*)d_out;

    const int B = 4, NU = 65536, NV = 16384;
    const int CH_U = NU / 128, CH_V = NV / 128;  // 512 / 128 chunks, all layers

    unsigned short* FT_u = (unsigned short*)d_ws;
    unsigned short* FT_v = FT_u + (size_t)B * NU * 128;
    unsigned short* wbb_u = FT_v + (size_t)B * NV * 128;
    unsigned short* wbb_v = wbb_u + (size_t)B * 65 * NU;
    float* part_u = (float*)(wbb_v + (size_t)B * 65 * NV);
    float* part_v = part_u + (size_t)B * CH_U * 64 * 66;
    float* momu = part_v + (size_t)B * CH_V * 64 * 66;
    float* momv = momu + B * 64 * 66;
    unsigned short* WuBf = (unsigned short*)(momv + B * 64 * 66);
    unsigned short* WvBf = WuBf + (size_t)B * 64 * 256;
    float* biasU = (float*)(WvBf + (size_t)B * 64 * 256);
    float* biasV = biasU + B * 64;
    float* wT = biasV + B * 64;
    size_t need_T = (size_t)((char*)(wT + 6 * 393216) - (char*)d_ws);
    int use_T = (ws_size >= need_T) ? 1 : 0;

    // prep fuses bases+fc0+layer-0 analysis (chbf eliminated)
    k_prep<2><<<dim3(NU / 128, B), 256, 0, stream>>>(nodes_u, modes, latent, nwu, u_in, fc0uw, fc0ub,
                                                     FT_u, wbb_u, part_u, NU);
    k_prep<3><<<dim3(NV / 128, B), 256, 0, stream>>>(nodes_v, modes, latent, nwv, v_in, fc0vw, fc0vb,
                                                     FT_v, wbb_v, part_v, NV);
    if (use_T)
        k_tw<<<dim3(192, 6), 256, 0, stream>>>(ewc, ews, uwc, uws, vwc, vws, wT);

    for (int l = 0; l < 3; ++l) {
        int do_v = (l < 2) ? 1 : 0;
        k_reduce2<<<dim3(130, 2 * B), 256, 0, stream>>>(part_u, part_v, momu, momv, CH_U, CH_V, B);
        if (use_T) {
            k_buildW<<<dim3(33, B), 64, 0, stream>>>(momu, momv,
                wT + 0 * 393216 + l * 131072, wT + 1 * 393216 + l * 131072, ew0 + (size_t)l * 64 * 64,
                wT + 2 * 393216 + l * 131072, wT + 3 * 393216 + l * 131072, uw0 + (size_t)l * 64 * 64,
                wT + 4 * 393216 + l * 131072, wT + 5 * 393216 + l * 131072, vw0 + (size_t)l * 64 * 64,
                wsuw + l * 64 * 64, wsub + l * 64, wsvw + l * 64 * 64, wsvb + l * 64,
                WuBf, WvBf, biasU, biasV, do_v);
        } else {
            k_buildW_slow<<<dim3(33, B), 64, 0, stream>>>(momu, momv,
                ewc + (size_t)l * 64 * 64 * 32, ews + (size_t)l * 64 * 64 * 32, ew0 + (size_t)l * 64 * 64,
                uwc + (size_t)l * 64 * 64 * 32, uws + (size_t)l * 64 * 64 * 32, uw0 + (size_t)l * 64 * 64,
                vwc + (size_t)l * 64 * 64 * 32, vws + (size_t)l * 64 * 64 * 32, vw0 + (size_t)l * 64 * 64,
                wsuw + l * 64 * 64, wsub + l * 64, wsvw + l * 64 * 64, wsvb + l * 64,
                WuBf, WvBf, biasU, biasV, do_v);
        }
        int nbu = NU / 128;
        int nbx = nbu + (do_v ? NV / 128 : 0);
        int do_mom = (l < 2) ? 1 : 0;
        int wft_v = (l == 0) ? 1 : 0;
        k_synth3<<<dim3(nbx, B), 256, 0, stream>>>(WuBf, WvBf, biasU, biasV, FT_u, FT_v,
                                                   wbb_u, wbb_v, part_u, part_v,
                                                   NU, NV, nbu, do_v /*act_u*/, wft_v, do_mom);
    }
    k_fc12<<<dim3(NU / 128, B), 256, 0, stream>>>(FT_u, fc1w, fc1b, fc2w, fc2b, out, NU);
}

// Round 13
// 465.077 us; speedup vs baseline: 1.2290x; 1.0377x over previous
//
#include <hip/hip_runtime.h>
#include <math.h>

#define PI2 6.283185307179586f

typedef __attribute__((ext_vector_type(8))) short bf16x8;
typedef __attribute__((ext_vector_type(4))) float f32x4;

__device__ __forceinline__ float gelu_f(float x) {
    return 0.5f * x * (1.0f + erff(x * 0.7071067811865476f));
}
__device__ __forceinline__ unsigned short f2bf(float f) {
    unsigned int u = __float_as_uint(f);
    u += 0x7FFFu + ((u >> 16) & 1u);
    return (unsigned short)(u >> 16);
}
__device__ __forceinline__ float bf2f(unsigned short h) {
    return __uint_as_float(((unsigned int)h) << 16);
}
__device__ __forceinline__ unsigned int pk(unsigned short a, unsigned short b) {
    return (unsigned int)a | ((unsigned int)b << 16);
}
__device__ __forceinline__ void wsplit(float w, unsigned short* dst) {
    unsigned short h = f2bf(w);
    dst[0] = h;
    dst[128] = f2bf(w - bf2f(h));
}

// ---- fused bases + fc0 + layer-0 analysis ----
template<int NIN>
__global__ __launch_bounds__(256) void k_prep(const float* __restrict__ nodes, const float* __restrict__ modes,
                                              const float* __restrict__ latent, const float* __restrict__ nw,
                                              const float* __restrict__ inp, const float* __restrict__ fcw,
                                              const float* __restrict__ fcb,
                                              unsigned short* __restrict__ FT, unsigned short* __restrict__ wbb,
                                              float* __restrict__ part, int N) {
    int b = blockIdx.y;
    int tid = threadIdx.x;
    int xl = tid & 127, half = tid >> 7;
    int x = blockIdx.x * 128 + xl;
    __shared__ unsigned short st_c[64][136];
    __shared__ unsigned short st_w[65][136];
    float s0 = 0.5f + 1.5f / (1.0f + expf(-latent[0]));
    float s1 = 0.5f + 1.5f / (1.0f + expf(-latent[1]));
    float n0 = nodes[((size_t)b * N + x) * 2 + 0];
    float n1 = nodes[((size_t)b * N + x) * 2 + 1];
    float wx = nw[(size_t)b * N + x];
    unsigned short* wb = wbb + (size_t)b * 65 * N + x;
    unsigned int fcos[8], fsin[8], fch[16];
    #pragma unroll
    for (int kk = 0; kk < 16; ++kk) {
        int k = half * 16 + kk;
        float m0 = modes[k * 2 + 0] * s0;
        float m1 = modes[k * 2 + 1] * s1;
        float t = PI2 * (n0 * m0 + n1 * m1);
        float s, c;
        sincosf(t, &s, &c);
        unsigned short hc = f2bf(c), hs = f2bf(s);
        if (kk & 1) { fcos[kk >> 1] |= ((unsigned int)hc << 16); fsin[kk >> 1] |= ((unsigned int)hs << 16); }
        else        { fcos[kk >> 1] = hc;                         fsin[kk >> 1] = hs; }
        unsigned short hcw = f2bf(c * wx), hsw = f2bf(s * wx);
        st_w[k][xl] = hcw;
        st_w[32 + k][xl] = hsw;
        wb[(size_t)k * N] = hcw;
        wb[(size_t)(32 + k) * N] = hsw;
    }
    if (half) {
        unsigned short hw = f2bf(wx);
        st_w[64][xl] = hw;
        wb[(size_t)64 * N] = hw;
    }
    float xi[NIN];
    #pragma unroll
    for (int i = 0; i < NIN; ++i) xi[i] = inp[((size_t)b * N + x) * NIN + i];
    #pragma unroll
    for (int cc = 0; cc < 32; ++cc) {
        int c = half * 32 + cc;
        float a = fcb[c];
        #pragma unroll
        for (int i = 0; i < NIN; ++i) a += fcw[c * NIN + i] * xi[i];
        unsigned short h = f2bf(a);
        st_c[c][xl] = h;
        if (cc & 1) fch[cc >> 1] |= ((unsigned int)h << 16);
        else fch[cc >> 1] = h;
    }
    unsigned int* fr = (unsigned int*)(FT + ((size_t)b * N + x) * 128);
    #pragma unroll
    for (int i = 0; i < 8; ++i) fr[half * 8 + i] = fcos[i];
    #pragma unroll
    for (int i = 0; i < 8; ++i) fr[16 + half * 8 + i] = fsin[i];
    #pragma unroll
    for (int i = 0; i < 16; ++i) fr[32 + half * 16 + i] = fch[i];
    __syncthreads();
    int lane = tid & 63, wv = tid >> 6;
    int lm = lane & 15, lg = lane >> 4;
    int ro = wv * 16;
    f32x4 acc[5] = {};
    #pragma unroll
    for (int xs = 0; xs < 128; xs += 32) {
        bf16x8 a = *(const bf16x8*)&st_c[ro + lm][xs + lg * 8];
        #pragma unroll
        for (int ct = 0; ct < 4; ++ct) {
            bf16x8 bw = *(const bf16x8*)&st_w[ct * 16 + lm][xs + lg * 8];
            acc[ct] = __builtin_amdgcn_mfma_f32_16x16x32_bf16(a, bw, acc[ct], 0, 0, 0);
        }
        bf16x8 wf = *(const bf16x8*)&st_w[64][xs + lg * 8];
        acc[4] = __builtin_amdgcn_mfma_f32_16x16x32_bf16(a, wf, acc[4], 0, 0, 0);
    }
    float* pb = part + (size_t)(b * (N / 128) + blockIdx.x) * 64 * 66;
    #pragma unroll
    for (int ct = 0; ct < 4; ++ct)
        #pragma unroll
        for (int j = 0; j < 4; ++j)
            pb[(ro + lg * 4 + j) * 66 + ct * 16 + lm] = acc[ct][j];
    if (lm == 0) {
        #pragma unroll
        for (int j = 0; j < 4; ++j) pb[(ro + lg * 4 + j) * 66 + 64] = acc[4][j];
    }
}

// ---- reduce partials u+v ----
__global__ __launch_bounds__(256) void k_reduce2(const float* __restrict__ part_u, const float* __restrict__ part_v,
                                                 float* __restrict__ momu, float* __restrict__ momv,
                                                 int chu, int chv, int B_) {
    int by = blockIdx.y;
    const float* p;
    float* m;
    int nch, b;
    if (by < B_) { b = by; p = part_u; m = momu; nch = chu; }
    else { b = by - B_; p = part_v; m = momv; nch = chv; }
    int eg = threadIdx.x >> 3;
    int sp = threadIdx.x & 7;
    int e = blockIdx.x * 32 + eg;
    __shared__ float red[32][8];
    float s = 0.f;
    int row = 0, col = 0;
    if (e < 64 * 65) {
        row = e / 65; col = e % 65;
        const float* pp = p + ((size_t)(b * nch) * 64 + row) * 66 + col;
        for (int c = sp; c < nch; c += 8)
            s += pp[(size_t)c * 64 * 66];
    }
    red[eg][sp] = s;
    __syncthreads();
    if (sp == 0 && e < 64 * 65) {
        float t = 0.f;
        #pragma unroll
        for (int i = 0; i < 8; ++i) t += red[eg][i];
        m[((size_t)b * 64 + row) * 66 + col] = t;
    }
}

// ---- transpose weights (l,i,o,k)->(l,k,i,o) ----
__global__ __launch_bounds__(256) void k_tw(const float* __restrict__ e_c, const float* __restrict__ e_s,
                                            const float* __restrict__ u_c, const float* __restrict__ u_s,
                                            const float* __restrict__ v_c, const float* __restrict__ v_s,
                                            float* __restrict__ oT) {
    int li = blockIdx.x;
    int a = blockIdx.y;
    const float* in;
    switch (a) {
        case 0: in = e_c; break;
        case 1: in = e_s; break;
        case 2: in = u_c; break;
        case 3: in = u_s; break;
        case 4: in = v_c; break;
        default: in = v_s; break;
    }
    float* outp = oT + (size_t)a * 393216;
    int l = li >> 6, i = li & 63;
    __shared__ float t[32][65];
    int tid = threadIdx.x;
    const float* ib = in + (size_t)l * 131072 + (size_t)i * 2048;
    #pragma unroll
    for (int r = 0; r < 8; ++r) {
        int e = r * 256 + tid;
        t[e & 31][e >> 5] = ib[e];
    }
    __syncthreads();
    float* ob = outp + (size_t)l * 131072 + (size_t)i * 64;
    #pragma unroll
    for (int r = 0; r < 8; ++r) {
        int e = r * 256 + tid;
        ob[(size_t)(e >> 6) * 4096 + (e & 63)] = t[e >> 6][e & 63];
    }
}

// ---- buildW -> WBf[b][o][hi128|lo128] bf16 + bias fp32 ----
__global__ void k_buildW(const float* __restrict__ momu, const float* __restrict__ momv,
                         const float* __restrict__ ecT, const float* __restrict__ esT, const float* __restrict__ ew0,
                         const float* __restrict__ ucT, const float* __restrict__ usT, const float* __restrict__ uw0,
                         const float* __restrict__ vcT, const float* __restrict__ vsT, const float* __restrict__ vw0,
                         const float* __restrict__ wsuw, const float* __restrict__ wsub,
                         const float* __restrict__ wsvw, const float* __restrict__ wsvb,
                         unsigned short* __restrict__ WuBf, unsigned short* __restrict__ WvBf,
                         float* __restrict__ biasU, float* __restrict__ biasV, int do_v) {
    int b = blockIdx.y, j = blockIdx.x, o = threadIdx.x;
    const float* mu = momu + (size_t)b * 64 * 66;
    const float* mv = momv + (size_t)b * 64 * 66;
    unsigned short* Wub = WuBf + ((size_t)b * 64 + o) * 256;
    unsigned short* Wvb = WvBf + ((size_t)b * 64 + o) * 256;
    if (j < 32) {
        int k = j;
        const float* ec = ecT + (size_t)k * 4096;
        const float* es = esT + (size_t)k * 4096;
        const float* uc = ucT + (size_t)k * 4096;
        const float* us = usT + (size_t)k * 4096;
        const float* vc = vcT + (size_t)k * 4096;
        const float* vs = vsT + (size_t)k * 4096;
        float fcu = 0, fsu = 0, fcv = 0, fsv = 0;
        for (int i = 0; i < 64; ++i) {
            float Scv = mv[i * 66 + k], Ssv = mv[i * 66 + 32 + k];
            float Scu = mu[i * 66 + k], Ssu = mu[i * 66 + 32 + k];
            int wi = i * 64 + o;
            float e_c = ec[wi], e_s = es[wi];
            float u_c = uc[wi], u_s = us[wi];
            fcu += Scv * e_c + Ssv * e_s + Scu * u_c + Ssu * u_s;
            fsu += Scv * e_s - Ssv * e_c + Scu * u_s - Ssu * u_c;
            if (do_v) {
                float v_c = vc[wi], v_s = vs[wi];
                fcv += Scv * v_c + Ssv * v_s;
                fsv += Scv * v_s - Ssv * v_c;
            }
        }
        wsplit(2.f * fcu, Wub + k);
        wsplit(-2.f * fsu, Wub + 32 + k);
        if (do_v) {
            wsplit(2.f * fcv, Wvb + k);
            wsplit(-2.f * fsv, Wvb + 32 + k);
        }
    } else {
        for (int c = 0; c < 64; ++c) wsplit(wsuw[o * 64 + c], Wub + 64 + c);
        float f0u = 0;
        for (int i = 0; i < 64; ++i)
            f0u += mv[i * 66 + 64] * ew0[i * 64 + o] + mu[i * 66 + 64] * uw0[i * 64 + o];
        biasU[b * 64 + o] = f0u + wsub[o];
        if (do_v) {
            for (int c = 0; c < 64; ++c) wsplit(wsvw[o * 64 + c], Wvb + 64 + c);
            float f0v = 0;
            for (int i = 0; i < 64; ++i) f0v += mv[i * 66 + 64] * vw0[i * 64 + o];
            biasV[b * 64 + o] = f0v + wsvb[o];
        }
    }
}

// ---- fallback buildW (original layout) ----
__global__ void k_buildW_slow(const float* __restrict__ momu, const float* __restrict__ momv,
                              const float* __restrict__ ewc, const float* __restrict__ ews, const float* __restrict__ ew0,
                              const float* __restrict__ uwc, const float* __restrict__ uws, const float* __restrict__ uw0,
                              const float* __restrict__ vwc, const float* __restrict__ vws, const float* __restrict__ vw0,
                              const float* __restrict__ wsuw, const float* __restrict__ wsub,
                              const float* __restrict__ wsvw, const float* __restrict__ wsvb,
                              unsigned short* __restrict__ WuBf, unsigned short* __restrict__ WvBf,
                              float* __restrict__ biasU, float* __restrict__ biasV, int do_v) {
    int b = blockIdx.y, j = blockIdx.x, o = threadIdx.x;
    const float* mu = momu + (size_t)b * 64 * 66;
    const float* mv = momv + (size_t)b * 64 * 66;
    unsigned short* Wub = WuBf + ((size_t)b * 64 + o) * 256;
    unsigned short* Wvb = WvBf + ((size_t)b * 64 + o) * 256;
    if (j < 32) {
        int k = j;
        float fcu = 0, fsu = 0, fcv = 0, fsv = 0;
        for (int i = 0; i < 64; ++i) {
            float Scv = mv[i * 66 + k], Ssv = mv[i * 66 + 32 + k];
            float Scu = mu[i * 66 + k], Ssu = mu[i * 66 + 32 + k];
            int wi = (i * 64 + o) * 32 + k;
            float ec = ewc[wi], es = ews[wi];
            float uc = uwc[wi], us = uws[wi];
            fcu += Scv * ec + Ssv * es + Scu * uc + Ssu * us;
            fsu += Scv * es - Ssv * ec + Scu * us - Ssu * uc;
            if (do_v) {
                float vc = vwc[wi], vs = vws[wi];
                fcv += Scv * vc + Ssv * vs;
                fsv += Scv * vs - Ssv * vc;
            }
        }
        wsplit(2.f * fcu, Wub + k);
        wsplit(-2.f * fsu, Wub + 32 + k);
        if (do_v) {
            wsplit(2.f * fcv, Wvb + k);
            wsplit(-2.f * fsv, Wvb + 32 + k);
        }
    } else {
        for (int c = 0; c < 64; ++c) wsplit(wsuw[o * 64 + c], Wub + 64 + c);
        float f0u = 0;
        for (int i = 0; i < 64; ++i)
            f0u += mv[i * 66 + 64] * ew0[i * 64 + o] + mu[i * 66 + 64] * uw0[i * 64 + o];
        biasU[b * 64 + o] = f0u + wsub[o];
        if (do_v) {
            for (int c = 0; c < 64; ++c) wsplit(wsvw[o * 64 + c], Wvb + 64 + c);
            float f0v = 0;
            for (int i = 0; i < 64; ++i) f0v += mv[i * 66 + 64] * vw0[i * 64 + o];
            biasV[b * 64 + o] = f0v + wsvb[o];
        }
    }
}

// ---- fused synthesis u+v + moment epilogue (layers 0,1) ----
__global__ __launch_bounds__(256) void k_synth3(const unsigned short* __restrict__ WuBf,
                                                const unsigned short* __restrict__ WvBf,
                                                const float* __restrict__ biasU, const float* __restrict__ biasV,
                                                unsigned short* FTu, unsigned short* FTv,
                                                const unsigned short* __restrict__ wbb_u,
                                                const unsigned short* __restrict__ wbb_v,
                                                float* __restrict__ part_u, float* __restrict__ part_v,
                                                int NU_, int NV_, int nbu, int act_u, int wft_v) {
    int bx = blockIdx.x, b = blockIdx.y, tid = threadIdx.x;
    const unsigned short* Wb;
    const float* bi;
    unsigned short* FT;
    const unsigned short* wb;
    float* pb;
    int N, act, wft, blk;
    if (bx < nbu) {
        blk = bx; Wb = WuBf; bi = biasU; FT = FTu; N = NU_;
        wb = wbb_u + (size_t)b * 65 * NU_;
        pb = part_u + (size_t)(b * (NU_ / 128) + blk) * 64 * 66;
        act = act_u; wft = 1;
    } else {
        blk = bx - nbu; Wb = WvBf; bi = biasV; FT = FTv; N = NV_;
        wb = wbb_v + (size_t)b * 65 * NV_;
        pb = part_v + (size_t)(b * (NV_ / 128) + blk) * 64 * 66;
        act = 1; wft = wft_v;
    }
    int lane = tid & 63, wv = tid >> 6;
    int lm = lane & 15, lg = lane >> 4;
    int ro = wv * 16;
    const unsigned short* Wrow = Wb + ((size_t)b * 64 + ro + lm) * 256;
    bf16x8 ahi[4], alo[4];
    #pragma unroll
    for (int kt = 0; kt < 4; ++kt) {
        ahi[kt] = *(const bf16x8*)(Wrow + kt * 32 + lg * 8);
        alo[kt] = *(const bf16x8*)(Wrow + 128 + kt * 32 + lg * 8);
    }
    float bias[4];
    #pragma unroll
    for (int j = 0; j < 4; ++j) bias[j] = bi[b * 64 + ro + lg * 4 + j];
    unsigned short* ftb = FT + (size_t)b * N * 128;
    __shared__ unsigned short st2[64][136];
    int r0 = ro + lg * 4;
    int x0 = blk * 128;
    f32x4 acc[8] = {};
    #pragma unroll
    for (int xt = 0; xt < 8; ++xt) {
        int x = x0 + xt * 16 + lm;
        const unsigned short* fp = ftb + (size_t)x * 128 + lg * 8;
        #pragma unroll
        for (int kt = 0; kt < 4; ++kt) {
            bf16x8 bf = *(const bf16x8*)(fp + kt * 32);
            acc[xt] = __builtin_amdgcn_mfma_f32_16x16x32_bf16(ahi[kt], bf, acc[xt], 0, 0, 0);
            acc[xt] = __builtin_amdgcn_mfma_f32_16x16x32_bf16(alo[kt], bf, acc[xt], 0, 0, 0);
        }
    }
    __syncthreads();  // all FT reads complete before in-place ch writes
    #pragma unroll
    for (int xt = 0; xt < 8; ++xt) {
        int xl = xt * 16 + lm;
        float v[4];
        #pragma unroll
        for (int j = 0; j < 4; ++j) {
            v[j] = acc[xt][j] + bias[j];
            if (act) v[j] = gelu_f(v[j]);
        }
        unsigned short h[4];
        #pragma unroll
        for (int j = 0; j < 4; ++j) h[j] = f2bf(v[j]);
        st2[r0 + 0][xl] = h[0];
        st2[r0 + 1][xl] = h[1];
        st2[r0 + 2][xl] = h[2];
        st2[r0 + 3][xl] = h[3];
        if (wft) {
            unsigned int* dst = (unsigned int*)(ftb + (size_t)(x0 + xl) * 128 + 64 + r0);
            dst[0] = pk(h[0], h[1]);
            dst[1] = pk(h[2], h[3]);
        }
    }
    __syncthreads();  // st2 visible to moment phase
    f32x4 macc[5] = {};
    #pragma unroll
    for (int xs = 0; xs < 128; xs += 32) {
        bf16x8 a = *(const bf16x8*)&st2[ro + lm][xs + lg * 8];
        #pragma unroll
        for (int ct = 0; ct < 4; ++ct) {
            bf16x8 bw = *(const bf16x8*)(wb + (size_t)(ct * 16 + lm) * N + x0 + xs + lg * 8);
            macc[ct] = __builtin_amdgcn_mfma_f32_16x16x32_bf16(a, bw, macc[ct], 0, 0, 0);
        }
        bf16x8 wf = *(const bf16x8*)(wb + (size_t)64 * N + x0 + xs + lg * 8);
        macc[4] = __builtin_amdgcn_mfma_f32_16x16x32_bf16(a, wf, macc[4], 0, 0, 0);
    }
    #pragma unroll
    for (int ct = 0; ct < 4; ++ct)
        #pragma unroll
        for (int j = 0; j < 4; ++j)
            pb[(r0 + j) * 66 + ct * 16 + lm] = macc[ct][j];
    if (lm == 0) {
        #pragma unroll
        for (int j = 0; j < 4; ++j) pb[(r0 + j) * 66 + 64] = macc[4][j];
    }
}

// ---- fused last-layer u-synthesis + fc1(gelu) + fc2 -> out (no FT writes, no moments) ----
__global__ __launch_bounds__(256) void k_synthfc(const unsigned short* __restrict__ WuBf,
                                                 const float* __restrict__ biasU,
                                                 const unsigned short* __restrict__ FTu,
                                                 const float* __restrict__ w1, const float* __restrict__ b1,
                                                 const float* __restrict__ w2, const float* __restrict__ b2,
                                                 float* __restrict__ out, int N) {
    int blk = blockIdx.x, b = blockIdx.y, tid = threadIdx.x;
    int lane = tid & 63, wv = tid >> 6;
    int lm = lane & 15, lg = lane >> 4;
    int ro = wv * 16;
    const unsigned short* Wrow = WuBf + ((size_t)b * 64 + ro + lm) * 256;
    bf16x8 ahi[4], alo[4];
    #pragma unroll
    for (int kt = 0; kt < 4; ++kt) {
        ahi[kt] = *(const bf16x8*)(Wrow + kt * 32 + lg * 8);
        alo[kt] = *(const bf16x8*)(Wrow + 128 + kt * 32 + lg * 8);
    }
    float bias[4];
    #pragma unroll
    for (int j = 0; j < 4; ++j) bias[j] = biasU[b * 64 + ro + lg * 4 + j];
    const unsigned short* ftb = FTu + (size_t)b * N * 128;
    __shared__ unsigned short st2t[128][72];   // [x][c] layout for fc B-frags
    __shared__ float red[4][8][16];
    int r0 = ro + lg * 4;
    int x0 = blk * 128;
    f32x4 acc[8] = {};
    #pragma unroll
    for (int xt = 0; xt < 8; ++xt) {
        int x = x0 + xt * 16 + lm;
        const unsigned short* fp = ftb + (size_t)x * 128 + lg * 8;
        #pragma unroll
        for (int kt = 0; kt < 4; ++kt) {
            bf16x8 bf = *(const bf16x8*)(fp + kt * 32);
            acc[xt] = __builtin_amdgcn_mfma_f32_16x16x32_bf16(ahi[kt], bf, acc[xt], 0, 0, 0);
            acc[xt] = __builtin_amdgcn_mfma_f32_16x16x32_bf16(alo[kt], bf, acc[xt], 0, 0, 0);
        }
    }
    // stage final-u tile (no gelu: last layer) in [x][c]
    #pragma unroll
    for (int xt = 0; xt < 8; ++xt) {
        int xl = xt * 16 + lm;
        float v0 = acc[xt][0] + bias[0];
        float v1 = acc[xt][1] + bias[1];
        float v2 = acc[xt][2] + bias[2];
        float v3 = acc[xt][3] + bias[3];
        *(unsigned int*)&st2t[xl][r0] = pk(f2bf(v0), f2bf(v1));
        *(unsigned int*)&st2t[xl][r0 + 2] = pk(f2bf(v2), f2bf(v3));
    }
    __syncthreads();
    // fc1+gelu+fc2 phase (w1 hi/lo-split MFMA, B-frags from LDS)
    int f0 = wv * 32;
    bf16x8 whi[2][2], wlo[2][2];
    #pragma unroll
    for (int ft = 0; ft < 2; ++ft)
        #pragma unroll
        for (int kt = 0; kt < 2; ++kt) {
            const float* wp = w1 + (size_t)(f0 + ft * 16 + lm) * 64 + kt * 32 + lg * 8;
            float tmp[8];
            *(float4*)&tmp[0] = *(const float4*)wp;
            *(float4*)&tmp[4] = *(const float4*)(wp + 4);
            #pragma unroll
            for (int i = 0; i < 8; ++i) {
                unsigned short h = f2bf(tmp[i]);
                whi[ft][kt][i] = (short)h;
                wlo[ft][kt][i] = (short)f2bf(tmp[i] - bf2f(h));
            }
        }
    float b1v[2][4], w2v[2][4];
    #pragma unroll
    for (int ft = 0; ft < 2; ++ft)
        #pragma unroll
        for (int j = 0; j < 4; ++j) {
            int f = f0 + ft * 16 + lg * 4 + j;
            b1v[ft][j] = b1[f];
            w2v[ft][j] = w2[f];
        }
    f32x4 facc[8][2] = {};
    #pragma unroll
    for (int xt = 0; xt < 8; ++xt) {
        int xl = xt * 16 + lm;
        bf16x8 bf0 = *(const bf16x8*)&st2t[xl][lg * 8];
        bf16x8 bf1 = *(const bf16x8*)&st2t[xl][32 + lg * 8];
        #pragma unroll
        for (int ft = 0; ft < 2; ++ft) {
            facc[xt][ft] = __builtin_amdgcn_mfma_f32_16x16x32_bf16(whi[ft][0], bf0, facc[xt][ft], 0, 0, 0);
            facc[xt][ft] = __builtin_amdgcn_mfma_f32_16x16x32_bf16(wlo[ft][0], bf0, facc[xt][ft], 0, 0, 0);
            facc[xt][ft] = __builtin_amdgcn_mfma_f32_16x16x32_bf16(whi[ft][1], bf1, facc[xt][ft], 0, 0, 0);
            facc[xt][ft] = __builtin_amdgcn_mfma_f32_16x16x32_bf16(wlo[ft][1], bf1, facc[xt][ft], 0, 0, 0);
        }
    }
    #pragma unroll
    for (int xt = 0; xt < 8; ++xt) {
        float s = 0.f;
        #pragma unroll
        for (int ft = 0; ft < 2; ++ft)
            #pragma unroll
            for (int j = 0; j < 4; ++j) {
                float v = facc[xt][ft][j] + b1v[ft][j];
                s += w2v[ft][j] * gelu_f(v);
            }
        s += __shfl_xor(s, 16, 64);
        s += __shfl_xor(s, 32, 64);
        if (lg == 0) red[wv][xt][lm] = s;
    }
    __syncthreads();
    if (tid < 128) {
        int xt = tid >> 4, lmm = tid & 15;
        float s = b2[0] + red[0][xt][lmm] + red[1][xt][lmm] + red[2][xt][lmm] + red[3][xt][lmm];
        out[(size_t)b * N + x0 + tid] = s;
    }
}

extern "C" void kernel_launch(void* const* d_in, const int* in_sizes, int n_in,
                              void* d_out, int out_size, void* d_ws, size_t ws_size,
                              hipStream_t stream) {
    const float* u_in = (const float*)d_in[0];
    const float* v_in = (const float*)d_in[1];
    const float* nodes_u = (const float*)d_in[3];
    const float* nodes_v = (const float*)d_in[4];
    const float* nwu = (const float*)d_in[5];
    const float* nwv = (const float*)d_in[6];
    const float* modes = (const float*)d_in[7];
    const float* latent = (const float*)d_in[8];
    const float* fc0uw = (const float*)d_in[9];
    const float* fc0ub = (const float*)d_in[10];
    const float* fc0vw = (const float*)d_in[11];
    const float* fc0vb = (const float*)d_in[12];
    const float* ewc = (const float*)d_in[13];
    const float* ews = (const float*)d_in[14];
    const float* ew0 = (const float*)d_in[15];
    const float* uwc = (const float*)d_in[16];
    const float* uws = (const float*)d_in[17];
    const float* uw0 = (const float*)d_in[18];
    const float* vwc = (const float*)d_in[19];
    const float* vws = (const float*)d_in[20];
    const float* vw0 = (const float*)d_in[21];
    const float* wsuw = (const float*)d_in[22];
    const float* wsub = (const float*)d_in[23];
    const float* wsvw = (const float*)d_in[24];
    const float* wsvb = (const float*)d_in[25];
    const float* fc1w = (const float*)d_in[26];
    const float* fc1b = (const float*)d_in[27];
    const float* fc2w = (const float*)d_in[28];
    const float* fc2b = (const float*)d_in[29];
    float* out = (float*)d_out;

    const int B = 4, NU = 65536, NV = 16384;
    const int CH_U = NU / 128, CH_V = NV / 128;

    unsigned short* FT_u = (unsigned short*)d_ws;
    unsigned short* FT_v = FT_u + (size_t)B * NU * 128;
    unsigned short* wbb_u = FT_v + (size_t)B * NV * 128;
    unsigned short* wbb_v = wbb_u + (size_t)B * 65 * NU;
    float* part_u = (float*)(wbb_v + (size_t)B * 65 * NV);
    float* part_v = part_u + (size_t)B * CH_U * 64 * 66;
    float* momu = part_v + (size_t)B * CH_V * 64 * 66;
    float* momv = momu + B * 64 * 66;
    unsigned short* WuBf = (unsigned short*)(momv + B * 64 * 66);
    unsigned short* WvBf = WuBf + (size_t)B * 64 * 256;
    float* biasU = (float*)(WvBf + (size_t)B * 64 * 256);
    float* biasV = biasU + B * 64;
    float* wT = biasV + B * 64;
    size_t need_T = (size_t)((char*)(wT + 6 * 393216) - (char*)d_ws);
    int use_T = (ws_size >= need_T) ? 1 : 0;

    k_prep<2><<<dim3(NU / 128, B), 256, 0, stream>>>(nodes_u, modes, latent, nwu, u_in, fc0uw, fc0ub,
                                                     FT_u, wbb_u, part_u, NU);
    k_prep<3><<<dim3(NV / 128, B), 256, 0, stream>>>(nodes_v, modes, latent, nwv, v_in, fc0vw, fc0vb,
                                                     FT_v, wbb_v, part_v, NV);
    if (use_T)
        k_tw<<<dim3(192, 6), 256, 0, stream>>>(ewc, ews, uwc, uws, vwc, vws, wT);

    for (int l = 0; l < 3; ++l) {
        int do_v = (l < 2) ? 1 : 0;
        k_reduce2<<<dim3(130, 2 * B), 256, 0, stream>>>(part_u, part_v, momu, momv, CH_U, CH_V, B);
        if (use_T) {
            k_buildW<<<dim3(33, B), 64, 0, stream>>>(momu, momv,
                wT + 0 * 393216 + l * 131072, wT + 1 * 393216 + l * 131072, ew0 + (size_t)l * 64 * 64,
                wT + 2 * 393216 + l * 131072, wT + 3 * 393216 + l * 131072, uw0 + (size_t)l * 64 * 64,
                wT + 4 * 393216 + l * 131072, wT + 5 * 393216 + l * 131072, vw0 + (size_t)l * 64 * 64,
                wsuw + l * 64 * 64, wsub + l * 64, wsvw + l * 64 * 64, wsvb + l * 64,
                WuBf, WvBf, biasU, biasV, do_v);
        } else {
            k_buildW_slow<<<dim3(33, B), 64, 0, stream>>>(momu, momv,
                ewc + (size_t)l * 64 * 64 * 32, ews + (size_t)l * 64 * 64 * 32, ew0 + (size_t)l * 64 * 64,
                uwc + (size_t)l * 64 * 64 * 32, uws + (size_t)l * 64 * 64 * 32, uw0 + (size_t)l * 64 * 64,
                vwc + (size_t)l * 64 * 64 * 32, vws + (size_t)l * 64 * 64 * 32, vw0 + (size_t)l * 64 * 64,
                wsuw + l * 64 * 64, wsub + l * 64, wsvw + l * 64 * 64, wsvb + l * 64,
                WuBf, WvBf, biasU, biasV, do_v);
        }
        if (l < 2) {
            int nbu = NU / 128;
            int nbx = nbu + NV / 128;
            int wft_v = (l == 0) ? 1 : 0;
            k_synth3<<<dim3(nbx, B), 256, 0, stream>>>(WuBf, WvBf, biasU, biasV, FT_u, FT_v,
                                                       wbb_u, wbb_v, part_u, part_v,
                                                       NU, NV, nbu, 1 /*act_u*/, wft_v);
        } else {
            k_synthfc<<<dim3(NU / 128, B), 256, 0, stream>>>(WuBf, biasU, FT_u,
                                                             fc1w, fc1b, fc2w, fc2b, out, NU);
        }
    }
}